// Round 1
// baseline (685.106 us; speedup 1.0000x reference)
//
#include <hip/hip_runtime.h>

// ---------------------------------------------------------------------------
// TransformerXL decoder layer on gfx950. bf16 MFMA everywhere matmul-shaped.
// Shapes: QLEN=MLEN=1024, KLEN=2048, BSZ=2, D=1024, H=16, DH=64, DFF=4096.
// Row convention for [len,b,*] tensors: flat row = pos*2 + b (matches jnp).
// ---------------------------------------------------------------------------

typedef unsigned short u16;
typedef unsigned int   u32;
typedef __attribute__((ext_vector_type(8))) short bf16x8;   // MFMA A/B frag
typedef __attribute__((ext_vector_type(4))) float f32x4;    // MFMA C/D frag

struct alignas(16) U128 { u32 x[4]; };
struct alignas(16) F128 { float f[4]; };
struct alignas(8)  U64  { u32 x[2]; };

#define DEV static __device__ __forceinline__
#define MF(a, b, c) __builtin_amdgcn_mfma_f32_16x16x32_bf16((a), (b), (c), 0, 0, 0)

DEV u16 f2bf(float f) {                      // RNE fp32 -> bf16
  union { float f; u32 u; } v; v.f = f;
  u32 r = v.u + 0x7fffu + ((v.u >> 16) & 1u);
  return (u16)(r >> 16);
}
DEV float bf2f(u16 h) {
  union { u32 u; float f; } v; v.u = ((u32)h) << 16;
  return v.f;
}

// ---------------- LayerNorm over rows of 1024, f32 in -> bf16 out ----------
__global__ __launch_bounds__(256) void ln_rows(
    const float* __restrict__ src, const float* __restrict__ g,
    const float* __restrict__ b, u16* __restrict__ dst)
{
  int row = blockIdx.x, tid = threadIdx.x;
  F128 v = ((const F128*)(src + (size_t)row * 1024))[tid];
  float s = v.f[0] + v.f[1] + v.f[2] + v.f[3];
  float q = v.f[0]*v.f[0] + v.f[1]*v.f[1] + v.f[2]*v.f[2] + v.f[3]*v.f[3];
#pragma unroll
  for (int off = 1; off < 64; off <<= 1) {
    s += __shfl_xor(s, off); q += __shfl_xor(q, off);
  }
  __shared__ float sh[8];
  int wid = tid >> 6;
  if ((tid & 63) == 0) { sh[wid] = s; sh[4 + wid] = q; }
  __syncthreads();
  s = sh[0] + sh[1] + sh[2] + sh[3];
  q = sh[4] + sh[5] + sh[6] + sh[7];
  float mu = s * (1.0f / 1024.0f);
  float rs = rsqrtf(q * (1.0f / 1024.0f) - mu * mu + 1e-5f);
  F128 g4 = ((const F128*)g)[tid];
  F128 b4 = ((const F128*)b)[tid];
  union { u16 h[4]; U64 u; } o;
#pragma unroll
  for (int j = 0; j < 4; j++)
    o.h[j] = f2bf((v.f[j] - mu) * rs * g4.f[j] + b4.f[j]);
  *(U64*)(dst + (size_t)row * 1024 + tid * 4) = o.u;
}

// ---------------- W[K,N] f32 -> Wt[N,K] bf16 (64x64 LDS tiles) -------------
__global__ __launch_bounds__(256) void transpose_w(
    const float* __restrict__ W, u16* __restrict__ Wt, int K, int N)
{
  __shared__ float t[64][65];
  int k0 = blockIdx.x * 64, n0 = blockIdx.y * 64;
  int tid = threadIdx.x;
  int r = tid >> 6, c = tid & 63;
#pragma unroll
  for (int i = 0; i < 16; i++)
    t[r + i * 4][c] = W[(size_t)(k0 + r + i * 4) * N + n0 + c];
  __syncthreads();
#pragma unroll
  for (int i = 0; i < 16; i++) {
    int n = r + i * 4;
    Wt[(size_t)(n0 + n) * K + k0 + c] = f2bf(t[c][n]);
  }
}

// ---------------- flat f32 -> bf16 (pos_emb) -------------------------------
__global__ __launch_bounds__(256) void cvt_bf16(
    const float* __restrict__ s, u16* __restrict__ d, int n4)
{
  int i = blockIdx.x * 256 + threadIdx.x;
  if (i >= n4) return;
  F128 v = ((const F128*)s)[i];
  union { u16 h[4]; U64 u; } o;
#pragma unroll
  for (int j = 0; j < 4; j++) o.h[j] = f2bf(v.f[j]);
  ((U64*)d)[i] = o.u;
}

// ---------------- GEMM: C[M,N] = A[M,K]*Bt[N,K]^T (+epilogue) --------------
// EPI 0: bf16 out, +bias(if non-null)
// EPI 1: bf16 out, +bias, relu
// EPI 2: f32  out, +bias(if non-null), +resid
// 128x128 tile, BK=64, 4 waves (2x2 of 64x64), reg-staged LDS, padded stride.
template <int EPI>
__global__ __launch_bounds__(256, 2) void gemm_bt(
    const u16* __restrict__ A, const u16* __restrict__ Bt,
    u16* __restrict__ outb, float* __restrict__ outf,
    const float* __restrict__ bias, const float* __restrict__ resid,
    int M, int N, int K)
{
  __shared__ u16 As[128][72];
  __shared__ u16 Bs[128][72];
  int tid = threadIdx.x;
  int m0 = blockIdx.x * 128, n0 = blockIdx.y * 128;
  int lane = tid & 63, wid = tid >> 6;
  int wr = wid >> 1, wc = wid & 1;
  f32x4 acc[4][4] = {};

  int srow = tid >> 1;
  int scol = (tid & 1) * 32;
  const u16* Ap = A + (size_t)(m0 + srow) * K + scol;
  const u16* Bp = Bt + (size_t)(n0 + srow) * K + scol;

  for (int k0 = 0; k0 < K; k0 += 64) {
    U128 av[4], bv[4];
#pragma unroll
    for (int i = 0; i < 4; i++) {
      av[i] = *(const U128*)(Ap + k0 + i * 8);
      bv[i] = *(const U128*)(Bp + k0 + i * 8);
    }
    __syncthreads();   // prior iter's frag reads done before overwrite
#pragma unroll
    for (int i = 0; i < 4; i++) {
      *(U128*)&As[srow][scol + i * 8] = av[i];
      *(U128*)&Bs[srow][scol + i * 8] = bv[i];
    }
    __syncthreads();
    bf16x8 af[2][4], bfr[2][4];
#pragma unroll
    for (int kc = 0; kc < 2; kc++)
#pragma unroll
      for (int f = 0; f < 4; f++) {
        af[kc][f]  = *(const bf16x8*)&As[wr * 64 + f * 16 + (lane & 15)][kc * 32 + (lane >> 4) * 8];
        bfr[kc][f] = *(const bf16x8*)&Bs[wc * 64 + f * 16 + (lane & 15)][kc * 32 + (lane >> 4) * 8];
      }
#pragma unroll
    for (int kc = 0; kc < 2; kc++)
#pragma unroll
      for (int fi = 0; fi < 4; fi++)
#pragma unroll
        for (int fj = 0; fj < 4; fj++)
          acc[fi][fj] = MF(af[kc][fi], bfr[kc][fj], acc[fi][fj]);
  }

  // epilogue: C row = (lane>>4)*4+reg, col = lane&15 within each 16x16 frag
#pragma unroll
  for (int fi = 0; fi < 4; fi++)
#pragma unroll
    for (int fj = 0; fj < 4; fj++) {
      int col = n0 + wc * 64 + fj * 16 + (lane & 15);
      float bvv = (bias != nullptr) ? bias[col] : 0.0f;
#pragma unroll
      for (int r = 0; r < 4; r++) {
        int row = m0 + wr * 64 + fi * 16 + (lane >> 4) * 4 + r;
        float v = acc[fi][fj][r] + bvv;
        if constexpr (EPI == 1) v = fmaxf(v, 0.0f);
        if constexpr (EPI == 2) {
          v += resid[(size_t)row * N + col];
          outf[(size_t)row * N + col] = v;
        } else {
          outb[(size_t)row * N + col] = f2bf(v);
        }
      }
    }
}

// ---------------- extract V from heads into Vt[bh][d][j] --------------------
__global__ __launch_bounds__(256) void extract_vt(
    const u16* __restrict__ heads, u16* __restrict__ Vt)
{
  __shared__ u16 t[64][72];
  int jt = blockIdx.x;           // j tile (0..31)
  int bh = blockIdx.y;           // 0..31
  int b = bh >> 4, h = bh & 15;
  int tid = threadIdx.x;
  int row = tid >> 2;
  int cc = (tid & 3) * 16;
#pragma unroll
  for (int i = 0; i < 2; i++)
    *(U128*)&t[row][cc + i * 8] =
        *(const U128*)&heads[(size_t)((jt * 64 + row) * 2 + b) * 3072 + 2048 + h * 64 + cc + i * 8];
  __syncthreads();
  int jc = tid & 63, dr = tid >> 6;
#pragma unroll
  for (int i = 0; i < 16; i++) {
    int d = dr + i * 4;
    Vt[((size_t)bh * 64 + d) * 2048 + jt * 64 + jc] = t[jc][d];
  }
}

// ---------------- fused rel-attention (flash-style) ------------------------
// block = (b,h, 64 q rows); 4 waves x 16 rows. K-tiles of 64.
// BD band: S_BD[ii2,jj] = Qr . r_k[1023 + (j0+jj) - (i0+16w+ii2)]
//   per-wave BD[16x96] over d = Dw+dd, Dw = 1008+j0-i0-16w, dd = jj-ii2+15.
__global__ __launch_bounds__(256, 2) void attn_fwd(
    const u16* __restrict__ heads, const u16* __restrict__ rk,
    const u16* __restrict__ Vt, const float* __restrict__ rwb,
    const float* __restrict__ rrb, u16* __restrict__ attnout)
{
  __shared__ u16 Qw[64][72];
  __shared__ u16 Qr[64][72];
  __shared__ u16 Ks[64][72];
  __shared__ u16 Vs[64][72];       // transposed: [d][j]
  __shared__ u16 Rs[144][72];      // r band
  __shared__ u16 BDs[4][16][104];  // per-wave banded BD (bf16)
  __shared__ u16 Ps[64][72];       // P tiles

  int tid = threadIdx.x, lane = tid & 63, wid = tid >> 6;
  int i0 = blockIdx.x * 64;
  int bh = blockIdx.y;
  int b = bh >> 4, h = bh & 15;

  // stage Q with both biases added (f32 add, bf16 store)
  for (int c = tid; c < 512; c += 256) {
    int row = c >> 3, c8 = (c & 7) * 8;
    union { U128 v; u16 h[8]; } in, ow, orr;
    in.v = *(const U128*)&heads[(size_t)((1024 + i0 + row) * 2 + b) * 3072 + h * 64 + c8];
#pragma unroll
    for (int j = 0; j < 8; j++) {
      float q = bf2f(in.h[j]);
      ow.h[j]  = f2bf(q + rwb[h * 64 + c8 + j]);
      orr.h[j] = f2bf(q + rrb[h * 64 + c8 + j]);
    }
    *(U128*)&Qw[row][c8] = ow.v;
    *(U128*)&Qr[row][c8] = orr.v;
  }
  __syncthreads();

  bf16x8 qwf[2], qrf[2];
  int qrow = wid * 16 + (lane & 15);
#pragma unroll
  for (int kc = 0; kc < 2; kc++) {
    qwf[kc] = *(const bf16x8*)&Qw[qrow][kc * 32 + (lane >> 4) * 8];
    qrf[kc] = *(const bf16x8*)&Qr[qrow][kc * 32 + (lane >> 4) * 8];
  }

  float mrow[4], lrow[4];
  f32x4 o[4] = {};
#pragma unroll
  for (int r = 0; r < 4; r++) { mrow[r] = -1e30f; lrow[r] = 0.0f; }

  int ntiles = i0 / 64 + 17;      // covers j <= i0+63+1024
  int iq = i0 + wid * 16;

  for (int t = 0; t < ntiles; t++) {
    int j0 = t * 64;
    __syncthreads();              // previous tile's LDS reads done
    for (int c = tid; c < 512; c += 256) {   // K tile
      int row = c >> 3, c8 = (c & 7) * 8;
      *(U128*)&Ks[row][c8] =
          *(const U128*)&heads[(size_t)((j0 + row) * 2 + b) * 3072 + 1024 + h * 64 + c8];
    }
    for (int c = tid; c < 512; c += 256) {   // V^T tile
      int d = c >> 3, c8 = (c & 7) * 8;
      *(U128*)&Vs[d][c8] = *(const U128*)&Vt[((size_t)bh * 64 + d) * 2048 + j0 + c8];
    }
    int rbase = 960 + j0 - i0;               // R band (clamped; OOB rows masked)
    for (int c = tid; c < 1152; c += 256) {
      int row = c >> 3, c8 = (c & 7) * 8;
      int rr = rbase + row;
      rr = rr < 0 ? 0 : (rr > 2047 ? 2047 : rr);
      *(U128*)&Rs[row][c8] = *(const U128*)&rk[(size_t)rr * 1024 + h * 64 + c8];
    }
    __syncthreads();

    // AC = Qw . K^T  (S[16x64])
    f32x4 s[4] = {};
#pragma unroll
    for (int kc = 0; kc < 2; kc++)
#pragma unroll
      for (int fj = 0; fj < 4; fj++) {
        bf16x8 kf = *(const bf16x8*)&Ks[fj * 16 + (lane & 15)][kc * 32 + (lane >> 4) * 8];
        s[fj] = MF(qwf[kc], kf, s[fj]);
      }

    // BD banded [16x96] -> LDS (bf16); same-wave write->read, HW in-order
    int roff = 48 - wid * 16;
#pragma unroll
    for (int fj = 0; fj < 6; fj++) {
      f32x4 bd = {};
#pragma unroll
      for (int kc = 0; kc < 2; kc++) {
        bf16x8 rf = *(const bf16x8*)&Rs[roff + fj * 16 + (lane & 15)][kc * 32 + (lane >> 4) * 8];
        bd = MF(qrf[kc], rf, bd);
      }
#pragma unroll
      for (int r = 0; r < 4; r++)
        BDs[wid][(lane >> 4) * 4 + r][fj * 16 + (lane & 15)] = f2bf(bd[r]);
    }

    // merge + mask + online softmax
    float p[4][4], tmax[4];
#pragma unroll
    for (int r = 0; r < 4; r++) tmax[r] = -1e30f;
#pragma unroll
    for (int fj = 0; fj < 4; fj++)
#pragma unroll
      for (int r = 0; r < 4; r++) {
        int ii2 = (lane >> 4) * 4 + r;
        int jj = fj * 16 + (lane & 15);
        float v = (s[fj][r] + bf2f(BDs[wid][ii2][jj - ii2 + 15])) * 0.125f;
        if (j0 + jj > iq + ii2 + 1024) v = -1e30f;   // causal+mem mask
        p[fj][r] = v;
        tmax[r] = fmaxf(tmax[r], v);
      }
#pragma unroll
    for (int off = 1; off < 16; off <<= 1)
#pragma unroll
      for (int r = 0; r < 4; r++)
        tmax[r] = fmaxf(tmax[r], __shfl_xor(tmax[r], off));
    float mscale[4], psum[4];
#pragma unroll
    for (int r = 0; r < 4; r++) {
      float mn = fmaxf(mrow[r], tmax[r]);
      mscale[r] = __expf(mrow[r] - mn);
      mrow[r] = mn;
      psum[r] = 0.0f;
    }
#pragma unroll
    for (int fj = 0; fj < 4; fj++)
#pragma unroll
      for (int r = 0; r < 4; r++) {
        float e = __expf(p[fj][r] - mrow[r]);
        p[fj][r] = e;
        psum[r] += e;
      }
#pragma unroll
    for (int off = 1; off < 16; off <<= 1)
#pragma unroll
      for (int r = 0; r < 4; r++)
        psum[r] += __shfl_xor(psum[r], off);
#pragma unroll
    for (int r = 0; r < 4; r++) lrow[r] = lrow[r] * mscale[r] + psum[r];
#pragma unroll
    for (int fd = 0; fd < 4; fd++)
#pragma unroll
      for (int r = 0; r < 4; r++) o[fd][r] *= mscale[r];

    // P -> LDS (own 16 rows), then O += P.V
#pragma unroll
    for (int fj = 0; fj < 4; fj++)
#pragma unroll
      for (int r = 0; r < 4; r++)
        Ps[wid * 16 + (lane >> 4) * 4 + r][fj * 16 + (lane & 15)] = f2bf(p[fj][r]);
#pragma unroll
    for (int kc = 0; kc < 2; kc++) {
      bf16x8 pf = *(const bf16x8*)&Ps[wid * 16 + (lane & 15)][kc * 32 + (lane >> 4) * 8];
#pragma unroll
      for (int fd = 0; fd < 4; fd++) {
        bf16x8 vf = *(const bf16x8*)&Vs[fd * 16 + (lane & 15)][kc * 32 + (lane >> 4) * 8];
        o[fd] = MF(pf, vf, o[fd]);
      }
    }
  }

#pragma unroll
  for (int fd = 0; fd < 4; fd++)
#pragma unroll
    for (int r = 0; r < 4; r++) {
      int ii2 = (lane >> 4) * 4 + r;
      int row = (i0 + wid * 16 + ii2) * 2 + b;
      attnout[(size_t)row * 1024 + h * 64 + fd * 16 + (lane & 15)] = f2bf(o[fd][r] / lrow[r]);
    }
}

// ---------------------------------------------------------------------------
extern "C" void kernel_launch(void* const* d_in, const int* in_sizes, int n_in,
                              void* d_out, int out_size, void* d_ws, size_t ws_size,
                              hipStream_t stream)
{
  const float* input_ = (const float*)d_in[0];
  const float* mems   = (const float*)d_in[1];
  const float* pos    = (const float*)d_in[2];
  // d_in[3] = mask_tgt: analytic (j > i + 1024), never read
  const float* ln1g = (const float*)d_in[4];
  const float* ln1b = (const float*)d_in[5];
  const float* qkvw = (const float*)d_in[6];
  const float* qkvb = (const float*)d_in[7];
  const float* rw   = (const float*)d_in[8];
  const float* rwb  = (const float*)d_in[9];
  const float* rrb  = (const float*)d_in[10];
  const float* ow   = (const float*)d_in[11];
  const float* ln2g = (const float*)d_in[12];
  const float* ln2b = (const float*)d_in[13];
  const float* fw1  = (const float*)d_in[14];
  const float* fb1  = (const float*)d_in[15];
  const float* fw2  = (const float*)d_in[16];
  const float* fb2  = (const float*)d_in[17];
  float* out = (float*)d_out;

  char* w = (char*)d_ws;
  // workspace layout (bytes); later buffers alias dead earlier ones
  u16* WT_QKV = (u16*)(w + 0);          // [3072,1024] bf16   6291456
  u16* WT_R   = (u16*)(w + 6291456);    // [1024,1024]        2097152
  u16* WT_O   = (u16*)(w + 8388608);    // [1024,1024]        2097152
  u16* WT_F1  = (u16*)(w + 10485760);   // [4096,1024]        8388608
  u16* WT_F2  = (u16*)(w + 18874368);   // [1024,4096]        8388608
  u16* POSB   = (u16*)(w + 27262976);   // [2048,1024]        4194304
  u16* ATTN   = POSB;                   // alias: POSB dead after r_k GEMM
  u16* CATLN  = (u16*)(w + 31457280);   // [4096,1024]        8388608
  u16* HEADS  = (u16*)(w + 39845888);   // [4096,3072]        25165824
  u16* H1     = HEADS;                  // alias: heads dead after attention
  float* X    = (float*)(w + 56623104); // [2048,1024] f32    8388608 (heads tail)
  u16* RK     = (u16*)(w + 65011712);   // [2048,1024]        4194304
  u16* VT     = (u16*)(w + 69206016);   // [2,16,64,2048]     8388608
  u16* YN     = VT;                     // alias: VT dead after attention
  // total 77594624 bytes

  dim3 blk(256);

  // weight prep (fp32 -> bf16, transposed to [N,K])
  transpose_w<<<dim3(16, 48), blk, 0, stream>>>(qkvw, WT_QKV, 1024, 3072);
  transpose_w<<<dim3(16, 16), blk, 0, stream>>>(rw,   WT_R,   1024, 1024);
  transpose_w<<<dim3(16, 16), blk, 0, stream>>>(ow,   WT_O,   1024, 1024);
  transpose_w<<<dim3(16, 64), blk, 0, stream>>>(fw1,  WT_F1,  1024, 4096);
  transpose_w<<<dim3(64, 16), blk, 0, stream>>>(fw2,  WT_F2,  4096, 1024);
  cvt_bf16<<<dim3(2048), blk, 0, stream>>>(pos, POSB, 2048 * 1024 / 4);

  // pre-norm: catln rows 0..2047 = LN(mems), 2048..4095 = LN(input)
  ln_rows<<<dim3(2048), blk, 0, stream>>>(mems,   ln1g, ln1b, CATLN);
  ln_rows<<<dim3(2048), blk, 0, stream>>>(input_, ln1g, ln1b, CATLN + 2048 * 1024);

  // heads = catln @ qkv_w + qkv_b ; r_k = pos @ r_w
  gemm_bt<0><<<dim3(32, 24), blk, 0, stream>>>(CATLN, WT_QKV, HEADS, nullptr, qkvb, nullptr, 4096, 3072, 1024);
  gemm_bt<0><<<dim3(16, 8),  blk, 0, stream>>>(POSB,  WT_R,   RK,    nullptr, nullptr, nullptr, 2048, 1024, 1024);

  extract_vt<<<dim3(32, 32), blk, 0, stream>>>(HEADS, VT);
  attn_fwd<<<dim3(16, 32), blk, 0, stream>>>(HEADS, RK, VT, rwb, rrb, ATTN);

  // X = input + attn @ o_w
  gemm_bt<2><<<dim3(16, 8), blk, 0, stream>>>(ATTN, WT_O, nullptr, X, nullptr, input_, 2048, 1024, 1024);

  // FFN: out = X + relu(LN(X) @ w1 + b1) @ w2 + b2
  ln_rows<<<dim3(2048), blk, 0, stream>>>(X, ln2g, ln2b, YN);
  gemm_bt<1><<<dim3(16, 32), blk, 0, stream>>>(YN, WT_F1, H1, nullptr, fb1, nullptr, 2048, 4096, 1024);
  gemm_bt<2><<<dim3(16, 8),  blk, 0, stream>>>(H1, WT_F2, nullptr, out, fb2, X, 2048, 1024, 4096);
}

// Round 2
// 343.298 us; speedup vs baseline: 1.9957x; 1.9957x over previous
//
#include <hip/hip_runtime.h>

// ---------------------------------------------------------------------------
// TransformerXL decoder layer on gfx950. bf16 MFMA everywhere matmul-shaped.
// Shapes: QLEN=MLEN=1024, KLEN=2048, BSZ=2, D=1024, H=16, DH=64, DFF=4096.
// Row convention for [len,b,*] tensors: flat row = pos*2 + b (matches jnp).
// R2: m97-style global_load_lds staging in GEMM; split-K for N=1024 GEMMs.
// ---------------------------------------------------------------------------

typedef unsigned short u16;
typedef unsigned int   u32;
typedef __attribute__((ext_vector_type(8))) short bf16x8;   // MFMA A/B frag
typedef __attribute__((ext_vector_type(4))) float f32x4;    // MFMA C/D frag

struct alignas(16) U128 { u32 x[4]; };
struct alignas(16) F128 { float f[4]; };
struct alignas(8)  U64  { u32 x[2]; };

#define DEV static __device__ __forceinline__
#define MF(a, b, c) __builtin_amdgcn_mfma_f32_16x16x32_bf16((a), (b), (c), 0, 0, 0)

typedef __attribute__((address_space(1))) u32 as1_u32;
typedef __attribute__((address_space(3))) u32 as3_u32;
DEV void gload16(const void* g, void* l) {   // 16B/lane direct global->LDS
  __builtin_amdgcn_global_load_lds((as1_u32*)g, (as3_u32*)l, 16, 0, 0);
}

DEV u16 f2bf(float f) {                      // RNE fp32 -> bf16
  union { float f; u32 u; } v; v.f = f;
  u32 r = v.u + 0x7fffu + ((v.u >> 16) & 1u);
  return (u16)(r >> 16);
}
DEV float bf2f(u16 h) {
  union { u32 u; float f; } v; v.u = ((u32)h) << 16;
  return v.f;
}

// ---------------- LayerNorm over rows of 1024, f32 in -> bf16 out ----------
__global__ __launch_bounds__(256) void ln_rows(
    const float* __restrict__ src, const float* __restrict__ g,
    const float* __restrict__ b, u16* __restrict__ dst)
{
  int row = blockIdx.x, tid = threadIdx.x;
  F128 v = ((const F128*)(src + (size_t)row * 1024))[tid];
  float s = v.f[0] + v.f[1] + v.f[2] + v.f[3];
  float q = v.f[0]*v.f[0] + v.f[1]*v.f[1] + v.f[2]*v.f[2] + v.f[3]*v.f[3];
#pragma unroll
  for (int off = 1; off < 64; off <<= 1) {
    s += __shfl_xor(s, off); q += __shfl_xor(q, off);
  }
  __shared__ float sh[8];
  int wid = tid >> 6;
  if ((tid & 63) == 0) { sh[wid] = s; sh[4 + wid] = q; }
  __syncthreads();
  s = sh[0] + sh[1] + sh[2] + sh[3];
  q = sh[4] + sh[5] + sh[6] + sh[7];
  float mu = s * (1.0f / 1024.0f);
  float rs = rsqrtf(q * (1.0f / 1024.0f) - mu * mu + 1e-5f);
  F128 g4 = ((const F128*)g)[tid];
  F128 b4 = ((const F128*)b)[tid];
  union { u16 h[4]; U64 u; } o;
#pragma unroll
  for (int j = 0; j < 4; j++)
    o.h[j] = f2bf((v.f[j] - mu) * rs * g4.f[j] + b4.f[j]);
  *(U64*)(dst + (size_t)row * 1024 + tid * 4) = o.u;
}

// ---------------- W[K,N] f32 -> Wt[N,K] bf16 (64x64 LDS tiles) -------------
__global__ __launch_bounds__(256) void transpose_w(
    const float* __restrict__ W, u16* __restrict__ Wt, int K, int N)
{
  __shared__ float t[64][65];
  int k0 = blockIdx.x * 64, n0 = blockIdx.y * 64;
  int tid = threadIdx.x;
  int r = tid >> 6, c = tid & 63;
#pragma unroll
  for (int i = 0; i < 16; i++)
    t[r + i * 4][c] = W[(size_t)(k0 + r + i * 4) * N + n0 + c];
  __syncthreads();
#pragma unroll
  for (int i = 0; i < 16; i++) {
    int n = r + i * 4;
    Wt[(size_t)(n0 + n) * K + k0 + c] = f2bf(t[c][n]);
  }
}

// ---------------- flat f32 -> bf16 (pos_emb) -------------------------------
__global__ __launch_bounds__(256) void cvt_bf16(
    const float* __restrict__ s, u16* __restrict__ d, int n4)
{
  int i = blockIdx.x * 256 + threadIdx.x;
  if (i >= n4) return;
  F128 v = ((const F128*)s)[i];
  union { u16 h[4]; U64 u; } o;
#pragma unroll
  for (int j = 0; j < 4; j++) o.h[j] = f2bf(v.f[j]);
  ((U64*)d)[i] = o.u;
}

// ---------------- GEMM: C[M,N] = A[M,K]*Bt[N,K]^T (+epilogue) --------------
// m97 structure: 128x128 tile, BK=64, 4 waves (2x2 of 64x64), linear LDS,
// global_load_lds width=16 staging, 2 barriers per k-step.
// NSPLIT>1: blockIdx.z selects K-chunk; raw f32 partial to p{z}.
// NSPLIT==1: EPI 0 = bf16 out (+bias); EPI 1 = bf16 out, +bias, relu.
template <int EPI, int NSPLIT>
__global__ __launch_bounds__(256, 2) void gemm_bt(
    const u16* __restrict__ A, const u16* __restrict__ Bt,
    u16* __restrict__ outb, const float* __restrict__ bias,
    float* __restrict__ p0, float* __restrict__ p1,
    float* __restrict__ p2, float* __restrict__ p3,
    int M, int N, int K)
{
  __shared__ u16 As[128 * 64];
  __shared__ u16 Bs[128 * 64];
  int tid = threadIdx.x;
  int m0 = blockIdx.x * 128, n0 = blockIdx.y * 128;
  int lane = tid & 63, wid = tid >> 6;
  int wr = wid >> 1, wc = wid & 1;
  f32x4 acc[4][4] = {};

  const int Kc = K / NSPLIT;
  const int kbase = (NSPLIT > 1) ? (int)blockIdx.z * Kc : 0;

  // staging address: issue i covers rows [i*32, i*32+32); this thread's slot:
  // row = i*32 + wid*8 + (lane>>3), col = (lane&7)*8 (u16). LDS dest is the
  // wave-uniform base As + (i*4+wid)*512; HW adds lane*16B.
  const int lrow = wid * 8 + (lane >> 3);
  const int lcol = (lane & 7) * 8;
  const u16* Ag = A  + (size_t)(m0 + lrow) * K + kbase + lcol;
  const u16* Bg = Bt + (size_t)(n0 + lrow) * K + kbase + lcol;

  for (int k0 = 0; k0 < Kc; k0 += 64) {
#pragma unroll
    for (int i = 0; i < 4; i++) {
      gload16(Ag + (size_t)i * 32 * K + k0, &As[(i * 4 + wid) * 512]);
      gload16(Bg + (size_t)i * 32 * K + k0, &Bs[(i * 4 + wid) * 512]);
    }
    __syncthreads();   // drains vmcnt (gload_lds) + aligns waves
    bf16x8 af[2][4], bfr[2][4];
#pragma unroll
    for (int kc = 0; kc < 2; kc++)
#pragma unroll
      for (int f = 0; f < 4; f++) {
        af[kc][f]  = *(const bf16x8*)&As[(wr * 64 + f * 16 + (lane & 15)) * 64 + kc * 32 + (lane >> 4) * 8];
        bfr[kc][f] = *(const bf16x8*)&Bs[(wc * 64 + f * 16 + (lane & 15)) * 64 + kc * 32 + (lane >> 4) * 8];
      }
#pragma unroll
    for (int kc = 0; kc < 2; kc++)
#pragma unroll
      for (int fi = 0; fi < 4; fi++)
#pragma unroll
        for (int fj = 0; fj < 4; fj++)
          acc[fi][fj] = MF(af[kc][fi], bfr[kc][fj], acc[fi][fj]);
    __syncthreads();   // frag reads done before next tile overwrites LDS
  }

  // epilogue: C row = (lane>>4)*4+reg, col = lane&15 within each 16x16 frag
  float* part = nullptr;
  if constexpr (NSPLIT > 1) {
    part = (blockIdx.z == 0) ? p0 : (blockIdx.z == 1) ? p1
         : (blockIdx.z == 2) ? p2 : p3;
  }
#pragma unroll
  for (int fi = 0; fi < 4; fi++)
#pragma unroll
    for (int fj = 0; fj < 4; fj++) {
      int col = n0 + wc * 64 + fj * 16 + (lane & 15);
      float bvv = (NSPLIT == 1 && bias != nullptr) ? bias[col] : 0.0f;
#pragma unroll
      for (int r = 0; r < 4; r++) {
        int row = m0 + wr * 64 + fi * 16 + (lane >> 4) * 4 + r;
        float v = acc[fi][fj][r] + bvv;
        if constexpr (NSPLIT > 1) {
          part[(size_t)row * N + col] = v;
        } else {
          if constexpr (EPI == 1) v = fmaxf(v, 0.0f);
          outb[(size_t)row * N + col] = f2bf(v);
        }
      }
    }
}

// ---------------- split-K reduce ------------------------------------------
// EPI 0: bf16 out (no bias). EPI 2: f32 out = sum + bias(opt) + resid.
template <int NS, int EPI>
__global__ __launch_bounds__(256) void reduce_split(
    const float* __restrict__ p0, const float* __restrict__ p1,
    const float* __restrict__ p2, const float* __restrict__ p3,
    const float* __restrict__ bias, const float* __restrict__ resid,
    u16* __restrict__ outb, float* __restrict__ outf, int N)
{
  int e = (blockIdx.x * 256 + threadIdx.x) * 4;
  F128 a = *(const F128*)(p0 + e);
  F128 b = *(const F128*)(p1 + e);
  float v[4];
#pragma unroll
  for (int j = 0; j < 4; j++) v[j] = a.f[j] + b.f[j];
  if constexpr (NS == 4) {
    F128 c = *(const F128*)(p2 + e);
    F128 d = *(const F128*)(p3 + e);
#pragma unroll
    for (int j = 0; j < 4; j++) v[j] += c.f[j] + d.f[j];
  }
  if constexpr (EPI == 2) {
    F128 rv = *(const F128*)(resid + e);
    int col = e % N;
    F128 o;
#pragma unroll
    for (int j = 0; j < 4; j++) {
      float bv = (bias != nullptr) ? bias[col + j] : 0.0f;
      o.f[j] = v[j] + bv + rv.f[j];
    }
    *(F128*)(outf + e) = o;
  } else {
    union { u16 h[4]; U64 u; } o;
#pragma unroll
    for (int j = 0; j < 4; j++) o.h[j] = f2bf(v[j]);
    *(U64*)(outb + e) = o.u;
  }
}

// ---------------- extract V from heads into Vt[bh][d][j] --------------------
__global__ __launch_bounds__(256) void extract_vt(
    const u16* __restrict__ heads, u16* __restrict__ Vt)
{
  __shared__ u16 t[64][72];
  int jt = blockIdx.x;           // j tile (0..31)
  int bh = blockIdx.y;           // 0..31
  int b = bh >> 4, h = bh & 15;
  int tid = threadIdx.x;
  int row = tid >> 2;
  int cc = (tid & 3) * 16;
#pragma unroll
  for (int i = 0; i < 2; i++)
    *(U128*)&t[row][cc + i * 8] =
        *(const U128*)&heads[(size_t)((jt * 64 + row) * 2 + b) * 3072 + 2048 + h * 64 + cc + i * 8];
  __syncthreads();
  int jc = tid & 63, dr = tid >> 6;
#pragma unroll
  for (int i = 0; i < 16; i++) {
    int d = dr + i * 4;
    Vt[((size_t)bh * 64 + d) * 2048 + jt * 64 + jc] = t[jc][d];
  }
}

// ---------------- fused rel-attention (flash-style) ------------------------
// block = (b,h, 64 q rows); 4 waves x 16 rows. K-tiles of 64.
// BD band: S_BD[ii2,jj] = Qr . r_k[1023 + (j0+jj) - (i0+16w+ii2)]
//   per-wave BD[16x96] over d = Dw+dd, Dw = 1008+j0-i0-16w, dd = jj-ii2+15.
__global__ __launch_bounds__(256, 2) void attn_fwd(
    const u16* __restrict__ heads, const u16* __restrict__ rk,
    const u16* __restrict__ Vt, const float* __restrict__ rwb,
    const float* __restrict__ rrb, u16* __restrict__ attnout)
{
  __shared__ u16 Qw[64][72];
  __shared__ u16 Qr[64][72];
  __shared__ u16 Ks[64][72];
  __shared__ u16 Vs[64][72];       // transposed: [d][j]
  __shared__ u16 Rs[144][72];      // r band
  __shared__ u16 BDs[4][16][104];  // per-wave banded BD (bf16)
  __shared__ u16 Ps[64][72];       // P tiles

  int tid = threadIdx.x, lane = tid & 63, wid = tid >> 6;
  int i0 = blockIdx.x * 64;
  int bh = blockIdx.y;
  int b = bh >> 4, h = bh & 15;

  // stage Q with both biases added (f32 add, bf16 store)
  for (int c = tid; c < 512; c += 256) {
    int row = c >> 3, c8 = (c & 7) * 8;
    union { U128 v; u16 h[8]; } in, ow, orr;
    in.v = *(const U128*)&heads[(size_t)((1024 + i0 + row) * 2 + b) * 3072 + h * 64 + c8];
#pragma unroll
    for (int j = 0; j < 8; j++) {
      float q = bf2f(in.h[j]);
      ow.h[j]  = f2bf(q + rwb[h * 64 + c8 + j]);
      orr.h[j] = f2bf(q + rrb[h * 64 + c8 + j]);
    }
    *(U128*)&Qw[row][c8] = ow.v;
    *(U128*)&Qr[row][c8] = orr.v;
  }
  __syncthreads();

  bf16x8 qwf[2], qrf[2];
  int qrow = wid * 16 + (lane & 15);
#pragma unroll
  for (int kc = 0; kc < 2; kc++) {
    qwf[kc] = *(const bf16x8*)&Qw[qrow][kc * 32 + (lane >> 4) * 8];
    qrf[kc] = *(const bf16x8*)&Qr[qrow][kc * 32 + (lane >> 4) * 8];
  }

  float mrow[4], lrow[4];
  f32x4 o[4] = {};
#pragma unroll
  for (int r = 0; r < 4; r++) { mrow[r] = -1e30f; lrow[r] = 0.0f; }

  int ntiles = i0 / 64 + 17;      // covers j <= i0+63+1024
  int iq = i0 + wid * 16;

  for (int t = 0; t < ntiles; t++) {
    int j0 = t * 64;
    __syncthreads();              // previous tile's LDS reads done
    for (int c = tid; c < 512; c += 256) {   // K tile
      int row = c >> 3, c8 = (c & 7) * 8;
      *(U128*)&Ks[row][c8] =
          *(const U128*)&heads[(size_t)((j0 + row) * 2 + b) * 3072 + 1024 + h * 64 + c8];
    }
    for (int c = tid; c < 512; c += 256) {   // V^T tile
      int d = c >> 3, c8 = (c & 7) * 8;
      *(U128*)&Vs[d][c8] = *(const U128*)&Vt[((size_t)bh * 64 + d) * 2048 + j0 + c8];
    }
    int rbase = 960 + j0 - i0;               // R band (clamped; OOB rows masked)
    for (int c = tid; c < 1152; c += 256) {
      int row = c >> 3, c8 = (c & 7) * 8;
      int rr = rbase + row;
      rr = rr < 0 ? 0 : (rr > 2047 ? 2047 : rr);
      *(U128*)&Rs[row][c8] = *(const U128*)&rk[(size_t)rr * 1024 + h * 64 + c8];
    }
    __syncthreads();

    // AC = Qw . K^T  (S[16x64])
    f32x4 s[4] = {};
#pragma unroll
    for (int kc = 0; kc < 2; kc++)
#pragma unroll
      for (int fj = 0; fj < 4; fj++) {
        bf16x8 kf = *(const bf16x8*)&Ks[fj * 16 + (lane & 15)][kc * 32 + (lane >> 4) * 8];
        s[fj] = MF(qwf[kc], kf, s[fj]);
      }

    // BD banded [16x96] -> LDS (bf16); same-wave write->read, HW in-order
    int roff = 48 - wid * 16;
#pragma unroll
    for (int fj = 0; fj < 6; fj++) {
      f32x4 bd = {};
#pragma unroll
      for (int kc = 0; kc < 2; kc++) {
        bf16x8 rf = *(const bf16x8*)&Rs[roff + fj * 16 + (lane & 15)][kc * 32 + (lane >> 4) * 8];
        bd = MF(qrf[kc], rf, bd);
      }
#pragma unroll
      for (int r = 0; r < 4; r++)
        BDs[wid][(lane >> 4) * 4 + r][fj * 16 + (lane & 15)] = f2bf(bd[r]);
    }

    // merge + mask + online softmax
    float p[4][4], tmax[4];
#pragma unroll
    for (int r = 0; r < 4; r++) tmax[r] = -1e30f;
#pragma unroll
    for (int fj = 0; fj < 4; fj++)
#pragma unroll
      for (int r = 0; r < 4; r++) {
        int ii2 = (lane >> 4) * 4 + r;
        int jj = fj * 16 + (lane & 15);
        float v = (s[fj][r] + bf2f(BDs[wid][ii2][jj - ii2 + 15])) * 0.125f;
        if (j0 + jj > iq + ii2 + 1024) v = -1e30f;   // causal+mem mask
        p[fj][r] = v;
        tmax[r] = fmaxf(tmax[r], v);
      }
#pragma unroll
    for (int off = 1; off < 16; off <<= 1)
#pragma unroll
      for (int r = 0; r < 4; r++)
        tmax[r] = fmaxf(tmax[r], __shfl_xor(tmax[r], off));
    float mscale[4], psum[4];
#pragma unroll
    for (int r = 0; r < 4; r++) {
      float mn = fmaxf(mrow[r], tmax[r]);
      mscale[r] = __expf(mrow[r] - mn);
      mrow[r] = mn;
      psum[r] = 0.0f;
    }
#pragma unroll
    for (int fj = 0; fj < 4; fj++)
#pragma unroll
      for (int r = 0; r < 4; r++) {
        float e = __expf(p[fj][r] - mrow[r]);
        p[fj][r] = e;
        psum[r] += e;
      }
#pragma unroll
    for (int off = 1; off < 16; off <<= 1)
#pragma unroll
      for (int r = 0; r < 4; r++)
        psum[r] += __shfl_xor(psum[r], off);
#pragma unroll
    for (int r = 0; r < 4; r++) lrow[r] = lrow[r] * mscale[r] + psum[r];
#pragma unroll
    for (int fd = 0; fd < 4; fd++)
#pragma unroll
      for (int r = 0; r < 4; r++) o[fd][r] *= mscale[r];

    // P -> LDS (own 16 rows), then O += P.V
#pragma unroll
    for (int fj = 0; fj < 4; fj++)
#pragma unroll
      for (int r = 0; r < 4; r++)
        Ps[wid * 16 + (lane >> 4) * 4 + r][fj * 16 + (lane & 15)] = f2bf(p[fj][r]);
#pragma unroll
    for (int kc = 0; kc < 2; kc++) {
      bf16x8 pf = *(const bf16x8*)&Ps[wid * 16 + (lane & 15)][kc * 32 + (lane >> 4) * 8];
#pragma unroll
      for (int fd = 0; fd < 4; fd++) {
        bf16x8 vf = *(const bf16x8*)&Vs[fd * 16 + (lane & 15)][kc * 32 + (lane >> 4) * 8];
        o[fd] = MF(pf, vf, o[fd]);
      }
    }
  }

#pragma unroll
  for (int fd = 0; fd < 4; fd++)
#pragma unroll
    for (int r = 0; r < 4; r++) {
      int ii2 = (lane >> 4) * 4 + r;
      int row = (i0 + wid * 16 + ii2) * 2 + b;
      attnout[(size_t)row * 1024 + h * 64 + fd * 16 + (lane & 15)] = f2bf(o[fd][r] / lrow[r]);
    }
}

// ---------------------------------------------------------------------------
extern "C" void kernel_launch(void* const* d_in, const int* in_sizes, int n_in,
                              void* d_out, int out_size, void* d_ws, size_t ws_size,
                              hipStream_t stream)
{
  const float* input_ = (const float*)d_in[0];
  const float* mems   = (const float*)d_in[1];
  const float* pos    = (const float*)d_in[2];
  // d_in[3] = mask_tgt: analytic (j > i + 1024), never read
  const float* ln1g = (const float*)d_in[4];
  const float* ln1b = (const float*)d_in[5];
  const float* qkvw = (const float*)d_in[6];
  const float* qkvb = (const float*)d_in[7];
  const float* rw   = (const float*)d_in[8];
  const float* rwb  = (const float*)d_in[9];
  const float* rrb  = (const float*)d_in[10];
  const float* ow   = (const float*)d_in[11];
  const float* ln2g = (const float*)d_in[12];
  const float* ln2b = (const float*)d_in[13];
  const float* fw1  = (const float*)d_in[14];
  const float* fb1  = (const float*)d_in[15];
  const float* fw2  = (const float*)d_in[16];
  const float* fb2  = (const float*)d_in[17];
  float* out = (float*)d_out;

  char* w = (char*)d_ws;
  // workspace layout (bytes); later buffers alias dead earlier ones
  u16* WT_QKV = (u16*)(w + 0);          // [3072,1024] bf16   6291456
  u16* WT_R   = (u16*)(w + 6291456);    // [1024,1024]        2097152
  u16* WT_O   = (u16*)(w + 8388608);    // [1024,1024]        2097152
  u16* WT_F1  = (u16*)(w + 10485760);   // [4096,1024]        8388608
  u16* WT_F2  = (u16*)(w + 18874368);   // [1024,4096]        8388608
  u16* POSB   = (u16*)(w + 27262976);   // [2048,1024]        4194304
  u16* ATTN   = POSB;                   // alias: POSB dead after r_k GEMM
  u16* CATLN  = (u16*)(w + 31457280);   // [4096,1024]        8388608
  u16* HEADS  = (u16*)(w + 39845888);   // [4096,3072]        25165824
  u16* H1     = HEADS;                  // alias: heads dead after attention
  float* X    = (float*)(w + 56623104); // [2048,1024] f32    8388608 (heads tail)
  u16* RK     = (u16*)(w + 65011712);   // [2048,1024]        4194304
  u16* VT     = (u16*)(w + 69206016);   // [2,16,64,2048]     8388608
  u16* YN     = VT;                     // alias: VT dead after attention
  // total 77594624 bytes

  // split-K partial buffers (each 2048x1024 f32 = 8388608 B), aliasing dead
  // regions at the time the owning GEMM runs:
  float* RKP0 = (float*)(w + 31457280); // = CATLN (dead after QKV gemm)
  float* RKP1 = (float*)(w + 69206016); // = VT    (written later by extract_vt)
  float* OWP0 = (float*)(w + 39845888); // = HEADS head (dead after attn)
  float* OWP1 = (float*)(w + 48234496); // = HEADS +8.39MB
  float* F2P0 = (float*)(w + 0);        // = WT_QKV+WT_R (dead after attn/rk)
  float* F2P1 = (float*)(w + 10485760); // = WT_F1 (dead after f1 gemm)
  float* F2P2 = (float*)(w + 31457280); // = CATLN
  float* F2P3 = (float*)(w + 65011712); // = RK + YN-head (dead after f1)

  dim3 blk(256);

  // weight prep (fp32 -> bf16, transposed to [N,K])
  transpose_w<<<dim3(16, 48), blk, 0, stream>>>(qkvw, WT_QKV, 1024, 3072);
  transpose_w<<<dim3(16, 16), blk, 0, stream>>>(rw,   WT_R,   1024, 1024);
  transpose_w<<<dim3(16, 16), blk, 0, stream>>>(ow,   WT_O,   1024, 1024);
  transpose_w<<<dim3(16, 64), blk, 0, stream>>>(fw1,  WT_F1,  1024, 4096);
  transpose_w<<<dim3(64, 16), blk, 0, stream>>>(fw2,  WT_F2,  4096, 1024);
  cvt_bf16<<<dim3(2048), blk, 0, stream>>>(pos, POSB, 2048 * 1024 / 4);

  // pre-norm: catln rows 0..2047 = LN(mems), 2048..4095 = LN(input)
  ln_rows<<<dim3(2048), blk, 0, stream>>>(mems,   ln1g, ln1b, CATLN);
  ln_rows<<<dim3(2048), blk, 0, stream>>>(input_, ln1g, ln1b, CATLN + 2048 * 1024);

  // heads = catln @ qkv_w + qkv_b
  gemm_bt<0, 1><<<dim3(32, 24), blk, 0, stream>>>(
      CATLN, WT_QKV, HEADS, qkvb, nullptr, nullptr, nullptr, nullptr, 4096, 3072, 1024);
  // r_k = pos @ r_w (split-K 2; partials reuse CATLN which is now dead)
  gemm_bt<0, 2><<<dim3(16, 8, 2), blk, 0, stream>>>(
      POSB, WT_R, nullptr, nullptr, RKP0, RKP1, nullptr, nullptr, 2048, 1024, 1024);
  reduce_split<2, 0><<<dim3(2048), blk, 0, stream>>>(
      RKP0, RKP1, nullptr, nullptr, nullptr, nullptr, RK, nullptr, 1024);

  extract_vt<<<dim3(32, 32), blk, 0, stream>>>(HEADS, VT);
  attn_fwd<<<dim3(16, 32), blk, 0, stream>>>(HEADS, RK, VT, rwb, rrb, ATTN);

  // X = input + attn @ o_w  (split-K 2)
  gemm_bt<0, 2><<<dim3(16, 8, 2), blk, 0, stream>>>(
      ATTN, WT_O, nullptr, nullptr, OWP0, OWP1, nullptr, nullptr, 2048, 1024, 1024);
  reduce_split<2, 2><<<dim3(2048), blk, 0, stream>>>(
      OWP0, OWP1, nullptr, nullptr, nullptr, input_, nullptr, X, 1024);

  // FFN: out = X + relu(LN(X) @ w1 + b1) @ w2 + b2
  ln_rows<<<dim3(2048), blk, 0, stream>>>(X, ln2g, ln2b, YN);
  gemm_bt<1, 1><<<dim3(16, 32), blk, 0, stream>>>(
      YN, WT_F1, H1, fb1, nullptr, nullptr, nullptr, nullptr, 2048, 4096, 1024);
  gemm_bt<0, 4><<<dim3(16, 8, 4), blk, 0, stream>>>(
      H1, WT_F2, nullptr, nullptr, F2P0, F2P1, F2P2, F2P3, 2048, 1024, 4096);
  reduce_split<4, 2><<<dim3(2048), blk, 0, stream>>>(
      F2P0, F2P1, F2P2, F2P3, fb2, X, nullptr, out, 1024);
}

// Round 3
// 313.449 us; speedup vs baseline: 2.1857x; 1.0952x over previous
//
#include <hip/hip_runtime.h>

// ---------------------------------------------------------------------------
// TransformerXL decoder layer on gfx950. bf16 MFMA everywhere matmul-shaped.
// Shapes: QLEN=MLEN=1024, KLEN=2048, BSZ=2, D=1024, H=16, DH=64, DFF=4096.
// Row convention for [len,b,*] tensors: flat row = pos*2 + b (matches jnp).
// R3: gemm_bt -> double-buffered 2-phase (barrier AFTER mfma);
//     attn_fwd -> reg-prefetch staging (T14), BD via shuffle-rotate (no LDS
//     roundtrip), 128-row R band, per-CU load pairing, setprio around MFMA.
// ---------------------------------------------------------------------------

typedef unsigned short u16;
typedef unsigned int   u32;
typedef __attribute__((ext_vector_type(8))) short bf16x8;   // MFMA A/B frag
typedef __attribute__((ext_vector_type(4))) float f32x4;    // MFMA C/D frag

struct alignas(16) U128 { u32 x[4]; };
struct alignas(16) F128 { float f[4]; };
struct alignas(8)  U64  { u32 x[2]; };

#define DEV static __device__ __forceinline__
#define MF(a, b, c) __builtin_amdgcn_mfma_f32_16x16x32_bf16((a), (b), (c), 0, 0, 0)

typedef __attribute__((address_space(1))) u32 as1_u32;
typedef __attribute__((address_space(3))) u32 as3_u32;
DEV void gload16(const void* g, void* l) {   // 16B/lane direct global->LDS
  __builtin_amdgcn_global_load_lds((as1_u32*)g, (as3_u32*)l, 16, 0, 0);
}

DEV u16 f2bf(float f) {                      // RNE fp32 -> bf16
  union { float f; u32 u; } v; v.f = f;
  u32 r = v.u + 0x7fffu + ((v.u >> 16) & 1u);
  return (u16)(r >> 16);
}
DEV float bf2f(u16 h) {
  union { u32 u; float f; } v; v.u = ((u32)h) << 16;
  return v.f;
}

// ---------------- LayerNorm over rows of 1024, f32 in -> bf16 out ----------
__global__ __launch_bounds__(256) void ln_rows(
    const float* __restrict__ src, const float* __restrict__ g,
    const float* __restrict__ b, u16* __restrict__ dst)
{
  int row = blockIdx.x, tid = threadIdx.x;
  F128 v = ((const F128*)(src + (size_t)row * 1024))[tid];
  float s = v.f[0] + v.f[1] + v.f[2] + v.f[3];
  float q = v.f[0]*v.f[0] + v.f[1]*v.f[1] + v.f[2]*v.f[2] + v.f[3]*v.f[3];
#pragma unroll
  for (int off = 1; off < 64; off <<= 1) {
    s += __shfl_xor(s, off); q += __shfl_xor(q, off);
  }
  __shared__ float sh[8];
  int wid = tid >> 6;
  if ((tid & 63) == 0) { sh[wid] = s; sh[4 + wid] = q; }
  __syncthreads();
  s = sh[0] + sh[1] + sh[2] + sh[3];
  q = sh[4] + sh[5] + sh[6] + sh[7];
  float mu = s * (1.0f / 1024.0f);
  float rs = rsqrtf(q * (1.0f / 1024.0f) - mu * mu + 1e-5f);
  F128 g4 = ((const F128*)g)[tid];
  F128 b4 = ((const F128*)b)[tid];
  union { u16 h[4]; U64 u; } o;
#pragma unroll
  for (int j = 0; j < 4; j++)
    o.h[j] = f2bf((v.f[j] - mu) * rs * g4.f[j] + b4.f[j]);
  *(U64*)(dst + (size_t)row * 1024 + tid * 4) = o.u;
}

// ---------------- W[K,N] f32 -> Wt[N,K] bf16 (64x64 LDS tiles) -------------
__global__ __launch_bounds__(256) void transpose_w(
    const float* __restrict__ W, u16* __restrict__ Wt, int K, int N)
{
  __shared__ float t[64][65];
  int k0 = blockIdx.x * 64, n0 = blockIdx.y * 64;
  int tid = threadIdx.x;
  int r = tid >> 6, c = tid & 63;
#pragma unroll
  for (int i = 0; i < 16; i++)
    t[r + i * 4][c] = W[(size_t)(k0 + r + i * 4) * N + n0 + c];
  __syncthreads();
#pragma unroll
  for (int i = 0; i < 16; i++) {
    int n = r + i * 4;
    Wt[(size_t)(n0 + n) * K + k0 + c] = f2bf(t[c][n]);
  }
}

// ---------------- flat f32 -> bf16 (pos_emb) -------------------------------
__global__ __launch_bounds__(256) void cvt_bf16(
    const float* __restrict__ s, u16* __restrict__ d, int n4)
{
  int i = blockIdx.x * 256 + threadIdx.x;
  if (i >= n4) return;
  F128 v = ((const F128*)s)[i];
  union { u16 h[4]; U64 u; } o;
#pragma unroll
  for (int j = 0; j < 4; j++) o.h[j] = f2bf(v.f[j]);
  ((U64*)d)[i] = o.u;
}

// ---------------- GEMM: C[M,N] = A[M,K]*Bt[N,K]^T (+epilogue) --------------
// 2-phase double-buffered: stage(t+1) -> ds_read+MFMA(t) -> barrier (drains
// the in-flight stage, which overlapped the MFMAs). 128x128 tile, BK=64,
// 4 waves (2x2 of 64x64), linear LDS, global_load_lds width=16.
// NSPLIT>1: blockIdx.z selects K-chunk; raw f32 partial to p{z}.
template <int EPI, int NSPLIT>
__global__ __launch_bounds__(256, 2) void gemm_bt(
    const u16* __restrict__ A, const u16* __restrict__ Bt,
    u16* __restrict__ outb, const float* __restrict__ bias,
    float* __restrict__ p0, float* __restrict__ p1,
    float* __restrict__ p2, float* __restrict__ p3,
    int M, int N, int K)
{
  __shared__ u16 As[2][128 * 64];
  __shared__ u16 Bs[2][128 * 64];
  int tid = threadIdx.x;
  int m0 = blockIdx.x * 128, n0 = blockIdx.y * 128;
  int lane = tid & 63, wid = tid >> 6;
  int wr = wid >> 1, wc = wid & 1;
  f32x4 acc[4][4] = {};

  const int Kc = K / NSPLIT;
  const int kbase = (NSPLIT > 1) ? (int)blockIdx.z * Kc : 0;

  const int lrow = wid * 8 + (lane >> 3);
  const int lcol = (lane & 7) * 8;
  const u16* Ag = A  + (size_t)(m0 + lrow) * K + kbase + lcol;
  const u16* Bg = Bt + (size_t)(n0 + lrow) * K + kbase + lcol;

  auto stage = [&](int buf, int k0) {
#pragma unroll
    for (int i = 0; i < 4; i++) {
      gload16(Ag + (size_t)i * 32 * K + k0, &As[buf][(i * 4 + wid) * 512]);
      gload16(Bg + (size_t)i * 32 * K + k0, &Bs[buf][(i * 4 + wid) * 512]);
    }
  };

  stage(0, 0);
  __syncthreads();                    // prologue drain
  int cur = 0;
  for (int k0 = 0; k0 < Kc; k0 += 64) {
    if (k0 + 64 < Kc) stage(cur ^ 1, k0 + 64);
    bf16x8 af[2][4], bfr[2][4];
#pragma unroll
    for (int kc = 0; kc < 2; kc++)
#pragma unroll
      for (int f = 0; f < 4; f++) {
        af[kc][f]  = *(const bf16x8*)&As[cur][(wr * 64 + f * 16 + (lane & 15)) * 64 + kc * 32 + (lane >> 4) * 8];
        bfr[kc][f] = *(const bf16x8*)&Bs[cur][(wc * 64 + f * 16 + (lane & 15)) * 64 + kc * 32 + (lane >> 4) * 8];
      }
    __builtin_amdgcn_s_setprio(1);
#pragma unroll
    for (int kc = 0; kc < 2; kc++)
#pragma unroll
      for (int fi = 0; fi < 4; fi++)
#pragma unroll
        for (int fj = 0; fj < 4; fj++)
          acc[fi][fj] = MF(af[kc][fi], bfr[kc][fj], acc[fi][fj]);
    __builtin_amdgcn_s_setprio(0);
    __syncthreads();                  // reads done + next buf staged
    cur ^= 1;
  }

  float* part = nullptr;
  if constexpr (NSPLIT > 1) {
    part = (blockIdx.z == 0) ? p0 : (blockIdx.z == 1) ? p1
         : (blockIdx.z == 2) ? p2 : p3;
  }
#pragma unroll
  for (int fi = 0; fi < 4; fi++)
#pragma unroll
    for (int fj = 0; fj < 4; fj++) {
      int col = n0 + wc * 64 + fj * 16 + (lane & 15);
      float bvv = (NSPLIT == 1 && bias != nullptr) ? bias[col] : 0.0f;
#pragma unroll
      for (int r = 0; r < 4; r++) {
        int row = m0 + wr * 64 + fi * 16 + (lane >> 4) * 4 + r;
        float v = acc[fi][fj][r] + bvv;
        if constexpr (NSPLIT > 1) {
          part[(size_t)row * N + col] = v;
        } else {
          if constexpr (EPI == 1) v = fmaxf(v, 0.0f);
          outb[(size_t)row * N + col] = f2bf(v);
        }
      }
    }
}

// ---------------- split-K reduce ------------------------------------------
template <int NS, int EPI>
__global__ __launch_bounds__(256) void reduce_split(
    const float* __restrict__ p0, const float* __restrict__ p1,
    const float* __restrict__ p2, const float* __restrict__ p3,
    const float* __restrict__ bias, const float* __restrict__ resid,
    u16* __restrict__ outb, float* __restrict__ outf, int N)
{
  int e = (blockIdx.x * 256 + threadIdx.x) * 4;
  F128 a = *(const F128*)(p0 + e);
  F128 b = *(const F128*)(p1 + e);
  float v[4];
#pragma unroll
  for (int j = 0; j < 4; j++) v[j] = a.f[j] + b.f[j];
  if constexpr (NS == 4) {
    F128 c = *(const F128*)(p2 + e);
    F128 d = *(const F128*)(p3 + e);
#pragma unroll
    for (int j = 0; j < 4; j++) v[j] += c.f[j] + d.f[j];
  }
  if constexpr (EPI == 2) {
    F128 rv = *(const F128*)(resid + e);
    int col = e % N;
    F128 o;
#pragma unroll
    for (int j = 0; j < 4; j++) {
      float bv = (bias != nullptr) ? bias[col + j] : 0.0f;
      o.f[j] = v[j] + bv + rv.f[j];
    }
    *(F128*)(outf + e) = o;
  } else {
    union { u16 h[4]; U64 u; } o;
#pragma unroll
    for (int j = 0; j < 4; j++) o.h[j] = f2bf(v[j]);
    *(U64*)(outb + e) = o.u;
  }
}

// ---------------- extract V from heads into Vt[bh][d][j] --------------------
__global__ __launch_bounds__(256) void extract_vt(
    const u16* __restrict__ heads, u16* __restrict__ Vt)
{
  __shared__ u16 t[64][72];
  int jt = blockIdx.x;           // j tile (0..31)
  int bh = blockIdx.y;           // 0..31
  int b = bh >> 4, h = bh & 15;
  int tid = threadIdx.x;
  int row = tid >> 2;
  int cc = (tid & 3) * 16;
#pragma unroll
  for (int i = 0; i < 2; i++)
    *(U128*)&t[row][cc + i * 8] =
        *(const U128*)&heads[(size_t)((jt * 64 + row) * 2 + b) * 3072 + 2048 + h * 64 + cc + i * 8];
  __syncthreads();
  int jc = tid & 63, dr = tid >> 6;
#pragma unroll
  for (int i = 0; i < 16; i++) {
    int d = dr + i * 4;
    Vt[((size_t)bh * 64 + d) * 2048 + jt * 64 + jc] = t[jc][d];
  }
}

// ---------------- fused rel-attention (flash-style) ------------------------
// block = (b,h, 64 q rows); 4 waves x 16 rows. K-tiles of 64.
// BD band frags bd[5]: BD_band[ii2][dd] = Qr[ii2] . Rs[roffw+dd],
//   dd = jj - ii2 + 15 in [0,78]; consumer gathers the diagonal by a
//   per-(quarter,r) lane rotation (2 shfl + select), all in f32.
// Staging: reg-prefetch of tile t+1 issued before compute(t) (T14).
__global__ __launch_bounds__(256, 2) void attn_fwd(
    const u16* __restrict__ heads, const u16* __restrict__ rk,
    const u16* __restrict__ Vt, const float* __restrict__ rwb,
    const float* __restrict__ rrb, u16* __restrict__ attnout)
{
  __shared__ u16 Qw[64][72];
  __shared__ u16 Qr[64][72];
  __shared__ u16 Ks[64][72];
  __shared__ u16 Vs[64][72];       // transposed: [d][j]
  __shared__ u16 Rs[128][72];      // r band (exactly the 128 needed rows)
  __shared__ u16 Ps[64][72];       // P tiles

  int tid = threadIdx.x, lane = tid & 63, wid = tid >> 6;
  int xt = (int)blockIdx.x;
  int bh = blockIdx.y;
  if (bh >= 16) xt = 15 - xt;      // per-CU load pairing: work(x)+work(15-x)=49
  int i0 = xt * 64;
  int b = bh >> 4, h = bh & 15;

  // stage Q with both biases added (f32 add, bf16 store)
  for (int c = tid; c < 512; c += 256) {
    int row = c >> 3, c8 = (c & 7) * 8;
    union { U128 v; u16 h[8]; } in, ow, orr;
    in.v = *(const U128*)&heads[(size_t)((1024 + i0 + row) * 2 + b) * 3072 + h * 64 + c8];
#pragma unroll
    for (int j = 0; j < 8; j++) {
      float q = bf2f(in.h[j]);
      ow.h[j]  = f2bf(q + rwb[h * 64 + c8 + j]);
      orr.h[j] = f2bf(q + rrb[h * 64 + c8 + j]);
    }
    *(U128*)&Qw[row][c8] = ow.v;
    *(U128*)&Qr[row][c8] = orr.v;
  }

  int ntiles = i0 / 64 + 17;       // covers j <= i0+63+1024
  int iq = i0 + wid * 16;

  // ---- reg-prefetch staging ----
  const int prow = tid >> 3;       // 0..31
  const int pc8 = (tid & 7) * 8;
  const u16* Kg = heads + (size_t)(prow * 2 + b) * 3072 + 1024 + h * 64 + pc8;
  const u16* Vg = Vt + ((size_t)bh * 64 + prow) * 2048 + pc8;
  const u16* Rg = rk + h * 64 + pc8;
  U128 kreg[2], vreg[2], rreg[4];

  auto loadT = [&](int t) {
    int j0 = t * 64;
#pragma unroll
    for (int i = 0; i < 2; i++) {
      kreg[i] = *(const U128*)(Kg + (size_t)(j0 + 32 * i) * 2 * 3072);
      vreg[i] = *(const U128*)(Vg + (size_t)(32 * i) * 2048 + j0);
    }
    int rbase = 960 + j0 - i0;
#pragma unroll
    for (int i = 0; i < 4; i++) {
      int rr = rbase + prow + 32 * i;
      rr = rr < 0 ? 0 : (rr > 2047 ? 2047 : rr);   // clamped rows never consumed
      rreg[i] = *(const U128*)(Rg + (size_t)rr * 1024);
    }
  };
  auto writeT = [&]() {
#pragma unroll
    for (int i = 0; i < 2; i++) {
      *(U128*)&Ks[prow + 32 * i][pc8] = kreg[i];
      *(U128*)&Vs[prow + 32 * i][pc8] = vreg[i];
    }
#pragma unroll
    for (int i = 0; i < 4; i++)
      *(U128*)&Rs[prow + 32 * i][pc8] = rreg[i];
  };

  loadT(0);
  writeT();
  __syncthreads();                 // Q + tile-0 staged

  bf16x8 qwf[2], qrf[2];
  int qrow = wid * 16 + (lane & 15);
#pragma unroll
  for (int kc = 0; kc < 2; kc++) {
    qwf[kc] = *(const bf16x8*)&Qw[qrow][kc * 32 + (lane >> 4) * 8];
    qrf[kc] = *(const bf16x8*)&Qr[qrow][kc * 32 + (lane >> 4) * 8];
  }

  float mrow[4], lrow[4];
  f32x4 o[4] = {};
#pragma unroll
  for (int r = 0; r < 4; r++) { mrow[r] = -1e30f; lrow[r] = 0.0f; }

  const int roffw = 48 - wid * 16;
  const int g = lane >> 4, cc = lane & 15;

  for (int t = 0; t < ntiles; t++) {
    int j0 = t * 64;
    if (t + 1 < ntiles) loadT(t + 1);   // issue next-tile loads (hidden under compute)

    // AC = Qw . K^T  and BD band = Qr . R_band^T
    f32x4 sAC[4] = {};
    f32x4 bd[5] = {};
    __builtin_amdgcn_s_setprio(1);
#pragma unroll
    for (int kc = 0; kc < 2; kc++) {
#pragma unroll
      for (int fj = 0; fj < 4; fj++) {
        bf16x8 kf = *(const bf16x8*)&Ks[fj * 16 + (lane & 15)][kc * 32 + (lane >> 4) * 8];
        sAC[fj] = MF(qwf[kc], kf, sAC[fj]);
      }
#pragma unroll
      for (int fb = 0; fb < 5; fb++) {
        bf16x8 rf = *(const bf16x8*)&Rs[roffw + fb * 16 + (lane & 15)][kc * 32 + (lane >> 4) * 8];
        bd[fb] = MF(qrf[kc], rf, bd[fb]);
      }
    }
    __builtin_amdgcn_s_setprio(0);

    // merge AC + diagonal-gathered BD, mask, online softmax (all f32)
    float p[4][4], tmax[4];
#pragma unroll
    for (int r = 0; r < 4; r++) tmax[r] = -1e30f;
#pragma unroll
    for (int fj = 0; fj < 4; fj++)
#pragma unroll
      for (int r = 0; r < 4; r++) {
        int sh_ = 15 - 4 * g - r;                    // uniform per (quarter, r)
        int src = (lane & 48) | ((lane + sh_) & 15);
        float lo = __shfl(bd[fj][r], src);
        float hi = __shfl(bd[fj + 1][r], src);
        float bdv = (cc + sh_ < 16) ? lo : hi;
        int ii2 = 4 * g + r;
        int jj = fj * 16 + cc;
        float v = (sAC[fj][r] + bdv) * 0.125f;
        if (j0 + jj > iq + ii2 + 1024) v = -1e30f;   // causal+mem mask
        p[fj][r] = v;
        tmax[r] = fmaxf(tmax[r], v);
      }
#pragma unroll
    for (int off = 1; off < 16; off <<= 1)
#pragma unroll
      for (int r = 0; r < 4; r++)
        tmax[r] = fmaxf(tmax[r], __shfl_xor(tmax[r], off));
    float mscale[4], psum[4];
#pragma unroll
    for (int r = 0; r < 4; r++) {
      float mn = fmaxf(mrow[r], tmax[r]);
      mscale[r] = __expf(mrow[r] - mn);
      mrow[r] = mn;
      psum[r] = 0.0f;
    }
#pragma unroll
    for (int fj = 0; fj < 4; fj++)
#pragma unroll
      for (int r = 0; r < 4; r++) {
        float e = __expf(p[fj][r] - mrow[r]);
        p[fj][r] = e;
        psum[r] += e;
      }
#pragma unroll
    for (int off = 1; off < 16; off <<= 1)
#pragma unroll
      for (int r = 0; r < 4; r++)
        psum[r] += __shfl_xor(psum[r], off);
#pragma unroll
    for (int r = 0; r < 4; r++) lrow[r] = lrow[r] * mscale[r] + psum[r];
#pragma unroll
    for (int fd = 0; fd < 4; fd++)
#pragma unroll
      for (int r = 0; r < 4; r++) o[fd][r] *= mscale[r];

    // P -> LDS (own 16 rows, same-wave in-order), then O += P.V
#pragma unroll
    for (int fj = 0; fj < 4; fj++)
#pragma unroll
      for (int r = 0; r < 4; r++)
        Ps[wid * 16 + (lane >> 4) * 4 + r][fj * 16 + (lane & 15)] = f2bf(p[fj][r]);
    __builtin_amdgcn_s_setprio(1);
#pragma unroll
    for (int kc = 0; kc < 2; kc++) {
      bf16x8 pf = *(const bf16x8*)&Ps[wid * 16 + (lane & 15)][kc * 32 + (lane >> 4) * 8];
#pragma unroll
      for (int fd = 0; fd < 4; fd++) {
        bf16x8 vf = *(const bf16x8*)&Vs[fd * 16 + (lane & 15)][kc * 32 + (lane >> 4) * 8];
        o[fd] = MF(pf, vf, o[fd]);
      }
    }
    __builtin_amdgcn_s_setprio(0);

    __syncthreads();               // all waves done reading Ks/Vs/Rs
    if (t + 1 < ntiles) {
      writeT();                    // waits the prefetched loads, writes LDS
      __syncthreads();
    }
  }

#pragma unroll
  for (int fd = 0; fd < 4; fd++)
#pragma unroll
    for (int r = 0; r < 4; r++) {
      int ii2 = (lane >> 4) * 4 + r;
      int row = (i0 + wid * 16 + ii2) * 2 + b;
      attnout[(size_t)row * 1024 + h * 64 + fd * 16 + (lane & 15)] = f2bf(o[fd][r] / lrow[r]);
    }
}

// ---------------------------------------------------------------------------
extern "C" void kernel_launch(void* const* d_in, const int* in_sizes, int n_in,
                              void* d_out, int out_size, void* d_ws, size_t ws_size,
                              hipStream_t stream)
{
  const float* input_ = (const float*)d_in[0];
  const float* mems   = (const float*)d_in[1];
  const float* pos    = (const float*)d_in[2];
  // d_in[3] = mask_tgt: analytic (j > i + 1024), never read
  const float* ln1g = (const float*)d_in[4];
  const float* ln1b = (const float*)d_in[5];
  const float* qkvw = (const float*)d_in[6];
  const float* qkvb = (const float*)d_in[7];
  const float* rw   = (const float*)d_in[8];
  const float* rwb  = (const float*)d_in[9];
  const float* rrb  = (const float*)d_in[10];
  const float* ow   = (const float*)d_in[11];
  const float* ln2g = (const float*)d_in[12];
  const float* ln2b = (const float*)d_in[13];
  const float* fw1  = (const float*)d_in[14];
  const float* fb1  = (const float*)d_in[15];
  const float* fw2  = (const float*)d_in[16];
  const float* fb2  = (const float*)d_in[17];
  float* out = (float*)d_out;

  char* w = (char*)d_ws;
  // workspace layout (bytes); later buffers alias dead earlier ones
  u16* WT_QKV = (u16*)(w + 0);          // [3072,1024] bf16   6291456
  u16* WT_R   = (u16*)(w + 6291456);    // [1024,1024]        2097152
  u16* WT_O   = (u16*)(w + 8388608);    // [1024,1024]        2097152
  u16* WT_F1  = (u16*)(w + 10485760);   // [4096,1024]        8388608
  u16* WT_F2  = (u16*)(w + 18874368);   // [1024,4096]        8388608
  u16* POSB   = (u16*)(w + 27262976);   // [2048,1024]        4194304
  u16* ATTN   = POSB;                   // alias: POSB dead after r_k GEMM
  u16* CATLN  = (u16*)(w + 31457280);   // [4096,1024]        8388608
  u16* HEADS  = (u16*)(w + 39845888);   // [4096,3072]        25165824
  u16* H1     = HEADS;                  // alias: heads dead after attention
  float* X    = (float*)(w + 56623104); // [2048,1024] f32    8388608 (heads tail)
  u16* RK     = (u16*)(w + 65011712);   // [2048,1024]        4194304
  u16* VT     = (u16*)(w + 69206016);   // [2,16,64,2048]     8388608
  u16* YN     = VT;                     // alias: VT dead after attention
  // total 77594624 bytes

  // split-K partial buffers (each 2048x1024 f32 = 8388608 B), aliasing dead
  // regions at the time the owning GEMM runs:
  float* RKP0 = (float*)(w + 31457280); // = CATLN (dead after QKV gemm)
  float* RKP1 = (float*)(w + 69206016); // = VT    (written later by extract_vt)
  float* OWP0 = (float*)(w + 39845888); // = HEADS head (dead after attn)
  float* OWP1 = (float*)(w + 48234496); // = HEADS +8.39MB
  float* F2P0 = (float*)(w + 0);        // = WT_QKV+WT_R (dead after attn/rk)
  float* F2P1 = (float*)(w + 10485760); // = WT_F1 (dead after f1 gemm)
  float* F2P2 = (float*)(w + 31457280); // = CATLN
  float* F2P3 = (float*)(w + 65011712); // = RK + YN-head (dead after f1)

  dim3 blk(256);

  // weight prep (fp32 -> bf16, transposed to [N,K])
  transpose_w<<<dim3(16, 48), blk, 0, stream>>>(qkvw, WT_QKV, 1024, 3072);
  transpose_w<<<dim3(16, 16), blk, 0, stream>>>(rw,   WT_R,   1024, 1024);
  transpose_w<<<dim3(16, 16), blk, 0, stream>>>(ow,   WT_O,   1024, 1024);
  transpose_w<<<dim3(16, 64), blk, 0, stream>>>(fw1,  WT_F1,  1024, 4096);
  transpose_w<<<dim3(64, 16), blk, 0, stream>>>(fw2,  WT_F2,  4096, 1024);
  cvt_bf16<<<dim3(2048), blk, 0, stream>>>(pos, POSB, 2048 * 1024 / 4);

  // pre-norm: catln rows 0..2047 = LN(mems), 2048..4095 = LN(input)
  ln_rows<<<dim3(2048), blk, 0, stream>>>(mems,   ln1g, ln1b, CATLN);
  ln_rows<<<dim3(2048), blk, 0, stream>>>(input_, ln1g, ln1b, CATLN + 2048 * 1024);

  // heads = catln @ qkv_w + qkv_b
  gemm_bt<0, 1><<<dim3(32, 24), blk, 0, stream>>>(
      CATLN, WT_QKV, HEADS, qkvb, nullptr, nullptr, nullptr, nullptr, 4096, 3072, 1024);
  // r_k = pos @ r_w (split-K 2; partials reuse CATLN which is now dead)
  gemm_bt<0, 2><<<dim3(16, 8, 2), blk, 0, stream>>>(
      POSB, WT_R, nullptr, nullptr, RKP0, RKP1, nullptr, nullptr, 2048, 1024, 1024);
  reduce_split<2, 0><<<dim3(2048), blk, 0, stream>>>(
      RKP0, RKP1, nullptr, nullptr, nullptr, nullptr, RK, nullptr, 1024);

  extract_vt<<<dim3(32, 32), blk, 0, stream>>>(HEADS, VT);
  attn_fwd<<<dim3(16, 32), blk, 0, stream>>>(HEADS, RK, VT, rwb, rrb, ATTN);

  // X = input + attn @ o_w  (split-K 2)
  gemm_bt<0, 2><<<dim3(16, 8, 2), blk, 0, stream>>>(
      ATTN, WT_O, nullptr, nullptr, OWP0, OWP1, nullptr, nullptr, 2048, 1024, 1024);
  reduce_split<2, 2><<<dim3(2048), blk, 0, stream>>>(
      OWP0, OWP1, nullptr, nullptr, nullptr, input_, nullptr, X, 1024);

  // FFN: out = X + relu(LN(X) @ w1 + b1) @ w2 + b2
  ln_rows<<<dim3(2048), blk, 0, stream>>>(X, ln2g, ln2b, YN);
  gemm_bt<1, 1><<<dim3(16, 32), blk, 0, stream>>>(
      YN, WT_F1, H1, fb1, nullptr, nullptr, nullptr, nullptr, 2048, 4096, 1024);
  gemm_bt<0, 4><<<dim3(16, 8, 4), blk, 0, stream>>>(
      H1, WT_F2, nullptr, nullptr, F2P0, F2P1, F2P2, F2P3, 2048, 1024, 4096);
  reduce_split<4, 2><<<dim3(2048), blk, 0, stream>>>(
      F2P0, F2P1, F2P2, F2P3, fb2, X, nullptr, out, 1024);
}

// Round 4
// 263.328 us; speedup vs baseline: 2.6017x; 1.1903x over previous
//
#include <hip/hip_runtime.h>

// ---------------------------------------------------------------------------
// TransformerXL decoder layer on gfx950. bf16 MFMA everywhere matmul-shaped.
// Shapes: QLEN=MLEN=1024, KLEN=2048, BSZ=2, D=1024, H=16, DH=64, DFF=4096.
// Row convention for [len,b,*] tensors: flat row = pos*2 + b (matches jnp).
// R4: attn_fwd restaged via global_load_lds (kills the R3 scratch spill),
//     double-buffered XOR-swizzled LDS, 1 barrier/tile, 74.8KB LDS
//     (2 blocks/CU), grid (bh,x) for per-XCD K/V L2 locality.
// ---------------------------------------------------------------------------

typedef unsigned short u16;
typedef unsigned int   u32;
typedef __attribute__((ext_vector_type(8))) short bf16x8;   // MFMA A/B frag
typedef __attribute__((ext_vector_type(4))) float f32x4;    // MFMA C/D frag

struct alignas(16) U128 { u32 x[4]; };
struct alignas(16) F128 { float f[4]; };
struct alignas(8)  U64  { u32 x[2]; };

#define DEV static __device__ __forceinline__
#define MF(a, b, c) __builtin_amdgcn_mfma_f32_16x16x32_bf16((a), (b), (c), 0, 0, 0)

typedef __attribute__((address_space(1))) u32 as1_u32;
typedef __attribute__((address_space(3))) u32 as3_u32;
DEV void gload16(const void* g, void* l) {   // 16B/lane direct global->LDS
  __builtin_amdgcn_global_load_lds((as1_u32*)g, (as3_u32*)l, 16, 0, 0);
}

DEV u16 f2bf(float f) {                      // RNE fp32 -> bf16
  union { float f; u32 u; } v; v.f = f;
  u32 r = v.u + 0x7fffu + ((v.u >> 16) & 1u);
  return (u16)(r >> 16);
}
DEV float bf2f(u16 h) {
  union { u32 u; float f; } v; v.u = ((u32)h) << 16;
  return v.f;
}

// ---------------- LayerNorm over rows of 1024, f32 in -> bf16 out ----------
__global__ __launch_bounds__(256) void ln_rows(
    const float* __restrict__ src, const float* __restrict__ g,
    const float* __restrict__ b, u16* __restrict__ dst)
{
  int row = blockIdx.x, tid = threadIdx.x;
  F128 v = ((const F128*)(src + (size_t)row * 1024))[tid];
  float s = v.f[0] + v.f[1] + v.f[2] + v.f[3];
  float q = v.f[0]*v.f[0] + v.f[1]*v.f[1] + v.f[2]*v.f[2] + v.f[3]*v.f[3];
#pragma unroll
  for (int off = 1; off < 64; off <<= 1) {
    s += __shfl_xor(s, off); q += __shfl_xor(q, off);
  }
  __shared__ float sh[8];
  int wid = tid >> 6;
  if ((tid & 63) == 0) { sh[wid] = s; sh[4 + wid] = q; }
  __syncthreads();
  s = sh[0] + sh[1] + sh[2] + sh[3];
  q = sh[4] + sh[5] + sh[6] + sh[7];
  float mu = s * (1.0f / 1024.0f);
  float rs = rsqrtf(q * (1.0f / 1024.0f) - mu * mu + 1e-5f);
  F128 g4 = ((const F128*)g)[tid];
  F128 b4 = ((const F128*)b)[tid];
  union { u16 h[4]; U64 u; } o;
#pragma unroll
  for (int j = 0; j < 4; j++)
    o.h[j] = f2bf((v.f[j] - mu) * rs * g4.f[j] + b4.f[j]);
  *(U64*)(dst + (size_t)row * 1024 + tid * 4) = o.u;
}

// ---------------- W[K,N] f32 -> Wt[N,K] bf16 (64x64 LDS tiles) -------------
__global__ __launch_bounds__(256) void transpose_w(
    const float* __restrict__ W, u16* __restrict__ Wt, int K, int N)
{
  __shared__ float t[64][65];
  int k0 = blockIdx.x * 64, n0 = blockIdx.y * 64;
  int tid = threadIdx.x;
  int r = tid >> 6, c = tid & 63;
#pragma unroll
  for (int i = 0; i < 16; i++)
    t[r + i * 4][c] = W[(size_t)(k0 + r + i * 4) * N + n0 + c];
  __syncthreads();
#pragma unroll
  for (int i = 0; i < 16; i++) {
    int n = r + i * 4;
    Wt[(size_t)(n0 + n) * K + k0 + c] = f2bf(t[c][n]);
  }
}

// ---------------- flat f32 -> bf16 (pos_emb) -------------------------------
__global__ __launch_bounds__(256) void cvt_bf16(
    const float* __restrict__ s, u16* __restrict__ d, int n4)
{
  int i = blockIdx.x * 256 + threadIdx.x;
  if (i >= n4) return;
  F128 v = ((const F128*)s)[i];
  union { u16 h[4]; U64 u; } o;
#pragma unroll
  for (int j = 0; j < 4; j++) o.h[j] = f2bf(v.f[j]);
  ((U64*)d)[i] = o.u;
}

// ---------------- GEMM: C[M,N] = A[M,K]*Bt[N,K]^T (+epilogue) --------------
// 2-phase double-buffered: stage(t+1) -> ds_read+MFMA(t) -> barrier.
// 128x128 tile, BK=64, 4 waves (2x2 of 64x64), linear LDS, gload_lds w=16.
template <int EPI, int NSPLIT>
__global__ __launch_bounds__(256, 2) void gemm_bt(
    const u16* __restrict__ A, const u16* __restrict__ Bt,
    u16* __restrict__ outb, const float* __restrict__ bias,
    float* __restrict__ p0, float* __restrict__ p1,
    float* __restrict__ p2, float* __restrict__ p3,
    int M, int N, int K)
{
  __shared__ u16 As[2][128 * 64];
  __shared__ u16 Bs[2][128 * 64];
  int tid = threadIdx.x;
  int m0 = blockIdx.x * 128, n0 = blockIdx.y * 128;
  int lane = tid & 63, wid = tid >> 6;
  int wr = wid >> 1, wc = wid & 1;
  f32x4 acc[4][4] = {};

  const int Kc = K / NSPLIT;
  const int kbase = (NSPLIT > 1) ? (int)blockIdx.z * Kc : 0;

  const int lrow = wid * 8 + (lane >> 3);
  const int lcol = (lane & 7) * 8;
  const u16* Ag = A  + (size_t)(m0 + lrow) * K + kbase + lcol;
  const u16* Bg = Bt + (size_t)(n0 + lrow) * K + kbase + lcol;

  auto stage = [&](int buf, int k0) {
#pragma unroll
    for (int i = 0; i < 4; i++) {
      gload16(Ag + (size_t)i * 32 * K + k0, &As[buf][(i * 4 + wid) * 512]);
      gload16(Bg + (size_t)i * 32 * K + k0, &Bs[buf][(i * 4 + wid) * 512]);
    }
  };

  stage(0, 0);
  __syncthreads();                    // prologue drain
  int cur = 0;
  for (int k0 = 0; k0 < Kc; k0 += 64) {
    if (k0 + 64 < Kc) stage(cur ^ 1, k0 + 64);
    bf16x8 af[2][4], bfr[2][4];
#pragma unroll
    for (int kc = 0; kc < 2; kc++)
#pragma unroll
      for (int f = 0; f < 4; f++) {
        af[kc][f]  = *(const bf16x8*)&As[cur][(wr * 64 + f * 16 + (lane & 15)) * 64 + kc * 32 + (lane >> 4) * 8];
        bfr[kc][f] = *(const bf16x8*)&Bs[cur][(wc * 64 + f * 16 + (lane & 15)) * 64 + kc * 32 + (lane >> 4) * 8];
      }
    __builtin_amdgcn_s_setprio(1);
#pragma unroll
    for (int kc = 0; kc < 2; kc++)
#pragma unroll
      for (int fi = 0; fi < 4; fi++)
#pragma unroll
        for (int fj = 0; fj < 4; fj++)
          acc[fi][fj] = MF(af[kc][fi], bfr[kc][fj], acc[fi][fj]);
    __builtin_amdgcn_s_setprio(0);
    __syncthreads();                  // reads done + next buf staged
    cur ^= 1;
  }

  float* part = nullptr;
  if constexpr (NSPLIT > 1) {
    part = (blockIdx.z == 0) ? p0 : (blockIdx.z == 1) ? p1
         : (blockIdx.z == 2) ? p2 : p3;
  }
#pragma unroll
  for (int fi = 0; fi < 4; fi++)
#pragma unroll
    for (int fj = 0; fj < 4; fj++) {
      int col = n0 + wc * 64 + fj * 16 + (lane & 15);
      float bvv = (NSPLIT == 1 && bias != nullptr) ? bias[col] : 0.0f;
#pragma unroll
      for (int r = 0; r < 4; r++) {
        int row = m0 + wr * 64 + fi * 16 + (lane >> 4) * 4 + r;
        float v = acc[fi][fj][r] + bvv;
        if constexpr (NSPLIT > 1) {
          part[(size_t)row * N + col] = v;
        } else {
          if constexpr (EPI == 1) v = fmaxf(v, 0.0f);
          outb[(size_t)row * N + col] = f2bf(v);
        }
      }
    }
}

// ---------------- split-K reduce ------------------------------------------
template <int NS, int EPI>
__global__ __launch_bounds__(256) void reduce_split(
    const float* __restrict__ p0, const float* __restrict__ p1,
    const float* __restrict__ p2, const float* __restrict__ p3,
    const float* __restrict__ bias, const float* __restrict__ resid,
    u16* __restrict__ outb, float* __restrict__ outf, int N)
{
  int e = (blockIdx.x * 256 + threadIdx.x) * 4;
  F128 a = *(const F128*)(p0 + e);
  F128 b = *(const F128*)(p1 + e);
  float v[4];
#pragma unroll
  for (int j = 0; j < 4; j++) v[j] = a.f[j] + b.f[j];
  if constexpr (NS == 4) {
    F128 c = *(const F128*)(p2 + e);
    F128 d = *(const F128*)(p3 + e);
#pragma unroll
    for (int j = 0; j < 4; j++) v[j] += c.f[j] + d.f[j];
  }
  if constexpr (EPI == 2) {
    F128 rv = *(const F128*)(resid + e);
    int col = e % N;
    F128 o;
#pragma unroll
    for (int j = 0; j < 4; j++) {
      float bv = (bias != nullptr) ? bias[col + j] : 0.0f;
      o.f[j] = v[j] + bv + rv.f[j];
    }
    *(F128*)(outf + e) = o;
  } else {
    union { u16 h[4]; U64 u; } o;
#pragma unroll
    for (int j = 0; j < 4; j++) o.h[j] = f2bf(v[j]);
    *(U64*)(outb + e) = o.u;
  }
}

// ---------------- extract V from heads into Vt[bh][d][j] --------------------
__global__ __launch_bounds__(256) void extract_vt(
    const u16* __restrict__ heads, u16* __restrict__ Vt)
{
  __shared__ u16 t[64][72];
  int jt = blockIdx.x;           // j tile (0..31)
  int bh = blockIdx.y;           // 0..31
  int b = bh >> 4, h = bh & 15;
  int tid = threadIdx.x;
  int row = tid >> 2;
  int cc = (tid & 3) * 16;
#pragma unroll
  for (int i = 0; i < 2; i++)
    *(U128*)&t[row][cc + i * 8] =
        *(const U128*)&heads[(size_t)((jt * 64 + row) * 2 + b) * 3072 + 2048 + h * 64 + cc + i * 8];
  __syncthreads();
  int jc = tid & 63, dr = tid >> 6;
#pragma unroll
  for (int i = 0; i < 16; i++) {
    int d = dr + i * 4;
    Vt[((size_t)bh * 64 + d) * 2048 + jt * 64 + jc] = t[jc][d];
  }
}

// ---------------- fused rel-attention (flash-style) ------------------------
// block = (b,h, 64 q rows); 4 waves x 16 rows. K-tiles of 64.
// LDS: double-buffered K[64][64] / V^T[64][64] / Rband[128][64], all
// column-XOR-swizzled (data[r][c] at lds[r][c ^ 8*(r&7)]), staged via
// global_load_lds with pre-swizzled global source. One barrier per tile.
// BD band frags bd[5]; diagonal gathered by per-(quarter,r) lane rotation.
__global__ __launch_bounds__(256, 2) void attn_fwd(
    const u16* __restrict__ heads, const u16* __restrict__ rk,
    const u16* __restrict__ Vt, const float* __restrict__ rwb,
    const float* __restrict__ rrb, u16* __restrict__ attnout)
{
  // layout (u16): buf b at b*16384: K @+0 (4096), V @+4096 (4096), R @+8192 (8192)
  // Ps @32768 (64x72). Q overlay @0 during init (Qw 64x72, Qr at +4608).
  __shared__ u16 lds[37376];

  int tid = threadIdx.x, lane = tid & 63, wid = tid >> 6;
  int bh = blockIdx.x;                  // linear%8 = bh%8 -> same-XCD blocks share K/V
  int y = (int)blockIdx.y;
  int xt = (y < 8) ? y : 23 - y;        // CU pairing: work(y)+work(y+8) = 49 tiles
  int i0 = xt * 64;
  int b = bh >> 4, h = bh & 15;

  u16* Ps = lds + 32768;
  u16* Qw = lds;
  u16* Qr = lds + 4608;

  // ---- Q staging (overlay region; f32 bias add, bf16 store) ----
  for (int c = tid; c < 512; c += 256) {
    int row = c >> 3, c8 = (c & 7) * 8;
    union { U128 v; u16 h[8]; } in, ow, orr;
    in.v = *(const U128*)&heads[(size_t)((1024 + i0 + row) * 2 + b) * 3072 + h * 64 + c8];
#pragma unroll
    for (int j = 0; j < 8; j++) {
      float q = bf2f(in.h[j]);
      ow.h[j]  = f2bf(q + rwb[h * 64 + c8 + j]);
      orr.h[j] = f2bf(q + rrb[h * 64 + c8 + j]);
    }
    *(U128*)&Qw[row * 72 + c8] = ow.v;
    *(U128*)&Qr[row * 72 + c8] = orr.v;
  }
  __syncthreads();

  bf16x8 qwf[2], qrf[2];
  int qrow = wid * 16 + (lane & 15);
#pragma unroll
  for (int kc = 0; kc < 2; kc++) {
    qwf[kc] = *(const bf16x8*)&Qw[qrow * 72 + kc * 32 + (lane >> 4) * 8];
    qrf[kc] = *(const bf16x8*)&Qr[qrow * 72 + kc * 32 + (lane >> 4) * 8];
  }
  __syncthreads();                 // overlay reads done before gload overwrites

  // ---- staging (global_load_lds, source-side XOR swizzle) ----
  const int srow = lane >> 3;                    // row within 8-row group
  const int scol = 8 * ((lane & 7) ^ srow);      // pre-swizzled source col (u16)

  auto stage = [&](int buf, int t) {
    int j0 = t * 64;
    u16* base = lds + buf * 16384;
#pragma unroll
    for (int i = 0; i < 2; i++) {               // K: rows g8*8+srow
      int g8 = wid * 2 + i;
      int jr = j0 + g8 * 8 + srow;
      gload16(heads + (size_t)(jr * 2 + b) * 3072 + 1024 + h * 64 + scol,
              base + g8 * 512);
    }
#pragma unroll
    for (int i = 0; i < 2; i++) {               // V^T: rows = d
      int g8 = wid * 2 + i;
      int dr = g8 * 8 + srow;
      gload16(Vt + ((size_t)bh * 64 + dr) * 2048 + j0 + scol,
              base + 4096 + g8 * 512);
    }
    int rbase = 960 + j0 - i0;                  // R band (clamped rows masked later)
#pragma unroll
    for (int i = 0; i < 4; i++) {
      int g8 = wid * 4 + i;
      int rr = rbase + g8 * 8 + srow;
      rr = rr < 0 ? 0 : (rr > 2047 ? 2047 : rr);
      gload16(rk + (size_t)rr * 1024 + h * 64 + scol,
              base + 8192 + g8 * 512);
    }
  };

  stage(0, 0);
  __syncthreads();                 // tile 0 staged

  float mrow[4], lrow[4];
  f32x4 o[4] = {};
#pragma unroll
  for (int r = 0; r < 4; r++) { mrow[r] = -1e30f; lrow[r] = 0.0f; }

  int nt = i0 / 64 + 17;           // covers j <= i0+63+1024
  int iq = i0 + wid * 16;
  const int roffw = 48 - wid * 16;
  const int g = lane >> 4, cc = lane & 15;
  const int rswz = 8 * (lane & 7); // read-side XOR (row&7 == lane&7 for all frags)

  for (int t = 0; t < nt; t++) {
    int j0 = t * 64;
    const u16* base = lds + (t & 1) * 16384;
    if (t + 1 < nt) stage((t + 1) & 1, t + 1);  // overlaps compute below

    const u16* Kb = base;
    const u16* Vb = base + 4096;
    const u16* Rb = base + 8192;

    // AC = Qw.K^T ; BD band = Qr.Rband^T
    f32x4 sAC[4] = {};
    f32x4 bd[5] = {};
    __builtin_amdgcn_s_setprio(1);
#pragma unroll
    for (int kc = 0; kc < 2; kc++) {
      int cb = (kc * 32 + g * 8) ^ rswz;
#pragma unroll
      for (int fj = 0; fj < 4; fj++) {
        bf16x8 kf = *(const bf16x8*)&Kb[(fj * 16 + (lane & 15)) * 64 + cb];
        sAC[fj] = MF(qwf[kc], kf, sAC[fj]);
      }
#pragma unroll
      for (int fb = 0; fb < 5; fb++) {
        bf16x8 rf = *(const bf16x8*)&Rb[(roffw + fb * 16 + (lane & 15)) * 64 + cb];
        bd[fb] = MF(qrf[kc], rf, bd[fb]);
      }
    }
    __builtin_amdgcn_s_setprio(0);

    // merge AC + diagonal-gathered BD, mask, online softmax (all f32)
    float p[4][4], tmax[4];
#pragma unroll
    for (int r = 0; r < 4; r++) tmax[r] = -1e30f;
#pragma unroll
    for (int fj = 0; fj < 4; fj++)
#pragma unroll
      for (int r = 0; r < 4; r++) {
        int sh_ = 15 - 4 * g - r;                    // uniform per (quarter, r)
        int src = (lane & 48) | ((lane + sh_) & 15);
        float lo = __shfl(bd[fj][r], src);
        float hi = __shfl(bd[fj + 1][r], src);
        float bdv = (cc + sh_ < 16) ? lo : hi;
        int ii2 = 4 * g + r;
        int jj = fj * 16 + cc;
        float v = (sAC[fj][r] + bdv) * 0.125f;
        if (j0 + jj > iq + ii2 + 1024) v = -1e30f;   // causal+mem mask
        p[fj][r] = v;
        tmax[r] = fmaxf(tmax[r], v);
      }
#pragma unroll
    for (int off = 1; off < 16; off <<= 1)
#pragma unroll
      for (int r = 0; r < 4; r++)
        tmax[r] = fmaxf(tmax[r], __shfl_xor(tmax[r], off));
    float mscale[4], psum[4];
#pragma unroll
    for (int r = 0; r < 4; r++) {
      float mn = fmaxf(mrow[r], tmax[r]);
      mscale[r] = __expf(mrow[r] - mn);
      mrow[r] = mn;
      psum[r] = 0.0f;
    }
#pragma unroll
    for (int fj = 0; fj < 4; fj++)
#pragma unroll
      for (int r = 0; r < 4; r++) {
        float e = __expf(p[fj][r] - mrow[r]);
        p[fj][r] = e;
        psum[r] += e;
      }
#pragma unroll
    for (int off = 1; off < 16; off <<= 1)
#pragma unroll
      for (int r = 0; r < 4; r++)
        psum[r] += __shfl_xor(psum[r], off);
#pragma unroll
    for (int r = 0; r < 4; r++) lrow[r] = lrow[r] * mscale[r] + psum[r];
#pragma unroll
    for (int fd = 0; fd < 4; fd++)
#pragma unroll
      for (int r = 0; r < 4; r++) o[fd][r] *= mscale[r];

    // P -> LDS (own 16 rows, same-wave in-order), then O += P.V
#pragma unroll
    for (int fj = 0; fj < 4; fj++)
#pragma unroll
      for (int r = 0; r < 4; r++)
        Ps[(wid * 16 + g * 4 + r) * 72 + fj * 16 + cc] = f2bf(p[fj][r]);
    __builtin_amdgcn_s_setprio(1);
#pragma unroll
    for (int kc = 0; kc < 2; kc++) {
      bf16x8 pf = *(const bf16x8*)&Ps[(wid * 16 + (lane & 15)) * 72 + kc * 32 + g * 8];
      int cb = (kc * 32 + g * 8) ^ rswz;
#pragma unroll
      for (int fd = 0; fd < 4; fd++) {
        bf16x8 vf = *(const bf16x8*)&Vb[(fd * 16 + (lane & 15)) * 64 + cb];
        o[fd] = MF(pf, vf, o[fd]);
      }
    }
    __builtin_amdgcn_s_setprio(0);

    __syncthreads();               // drains stage(t+1) + protects buf reuse
  }

#pragma unroll
  for (int fd = 0; fd < 4; fd++)
#pragma unroll
    for (int r = 0; r < 4; r++) {
      int ii2 = (lane >> 4) * 4 + r;
      int row = (i0 + wid * 16 + ii2) * 2 + b;
      attnout[(size_t)row * 1024 + h * 64 + fd * 16 + (lane & 15)] = f2bf(o[fd][r] / lrow[r]);
    }
}

// ---------------------------------------------------------------------------
extern "C" void kernel_launch(void* const* d_in, const int* in_sizes, int n_in,
                              void* d_out, int out_size, void* d_ws, size_t ws_size,
                              hipStream_t stream)
{
  const float* input_ = (const float*)d_in[0];
  const float* mems   = (const float*)d_in[1];
  const float* pos    = (const float*)d_in[2];
  // d_in[3] = mask_tgt: analytic (j > i + 1024), never read
  const float* ln1g = (const float*)d_in[4];
  const float* ln1b = (const float*)d_in[5];
  const float* qkvw = (const float*)d_in[6];
  const float* qkvb = (const float*)d_in[7];
  const float* rw   = (const float*)d_in[8];
  const float* rwb  = (const float*)d_in[9];
  const float* rrb  = (const float*)d_in[10];
  const float* ow   = (const float*)d_in[11];
  const float* ln2g = (const float*)d_in[12];
  const float* ln2b = (const float*)d_in[13];
  const float* fw1  = (const float*)d_in[14];
  const float* fb1  = (const float*)d_in[15];
  const float* fw2  = (const float*)d_in[16];
  const float* fb2  = (const float*)d_in[17];
  float* out = (float*)d_out;

  char* w = (char*)d_ws;
  // workspace layout (bytes); later buffers alias dead earlier ones
  u16* WT_QKV = (u16*)(w + 0);          // [3072,1024] bf16   6291456
  u16* WT_R   = (u16*)(w + 6291456);    // [1024,1024]        2097152
  u16* WT_O   = (u16*)(w + 8388608);    // [1024,1024]        2097152
  u16* WT_F1  = (u16*)(w + 10485760);   // [4096,1024]        8388608
  u16* WT_F2  = (u16*)(w + 18874368);   // [1024,4096]        8388608
  u16* POSB   = (u16*)(w + 27262976);   // [2048,1024]        4194304
  u16* ATTN   = POSB;                   // alias: POSB dead after r_k GEMM
  u16* CATLN  = (u16*)(w + 31457280);   // [4096,1024]        8388608
  u16* HEADS  = (u16*)(w + 39845888);   // [4096,3072]        25165824
  u16* H1     = HEADS;                  // alias: heads dead after attention
  float* X    = (float*)(w + 56623104); // [2048,1024] f32    8388608 (heads tail)
  u16* RK     = (u16*)(w + 65011712);   // [2048,1024]        4194304
  u16* VT     = (u16*)(w + 69206016);   // [2,16,64,2048]     8388608
  u16* YN     = VT;                     // alias: VT dead after attention
  // total 77594624 bytes

  // split-K partial buffers (each 2048x1024 f32 = 8388608 B), aliasing dead
  // regions at the time the owning GEMM runs:
  float* RKP0 = (float*)(w + 31457280); // = CATLN (dead after QKV gemm)
  float* RKP1 = (float*)(w + 69206016); // = VT    (written later by extract_vt)
  float* OWP0 = (float*)(w + 39845888); // = HEADS head (dead after attn)
  float* OWP1 = (float*)(w + 48234496); // = HEADS +8.39MB
  float* F2P0 = (float*)(w + 0);        // = WT_QKV+WT_R (dead after attn/rk)
  float* F2P1 = (float*)(w + 10485760); // = WT_F1 (dead after f1 gemm)
  float* F2P2 = (float*)(w + 31457280); // = CATLN
  float* F2P3 = (float*)(w + 65011712); // = RK + YN-head (dead after f1)

  dim3 blk(256);

  // weight prep (fp32 -> bf16, transposed to [N,K])
  transpose_w<<<dim3(16, 48), blk, 0, stream>>>(qkvw, WT_QKV, 1024, 3072);
  transpose_w<<<dim3(16, 16), blk, 0, stream>>>(rw,   WT_R,   1024, 1024);
  transpose_w<<<dim3(16, 16), blk, 0, stream>>>(ow,   WT_O,   1024, 1024);
  transpose_w<<<dim3(16, 64), blk, 0, stream>>>(fw1,  WT_F1,  1024, 4096);
  transpose_w<<<dim3(64, 16), blk, 0, stream>>>(fw2,  WT_F2,  4096, 1024);
  cvt_bf16<<<dim3(2048), blk, 0, stream>>>(pos, POSB, 2048 * 1024 / 4);

  // pre-norm: catln rows 0..2047 = LN(mems), 2048..4095 = LN(input)
  ln_rows<<<dim3(2048), blk, 0, stream>>>(mems,   ln1g, ln1b, CATLN);
  ln_rows<<<dim3(2048), blk, 0, stream>>>(input_, ln1g, ln1b, CATLN + 2048 * 1024);

  // heads = catln @ qkv_w + qkv_b
  gemm_bt<0, 1><<<dim3(32, 24), blk, 0, stream>>>(
      CATLN, WT_QKV, HEADS, qkvb, nullptr, nullptr, nullptr, nullptr, 4096, 3072, 1024);
  // r_k = pos @ r_w (split-K 2; partials reuse CATLN which is now dead)
  gemm_bt<0, 2><<<dim3(16, 8, 2), blk, 0, stream>>>(
      POSB, WT_R, nullptr, nullptr, RKP0, RKP1, nullptr, nullptr, 2048, 1024, 1024);
  reduce_split<2, 0><<<dim3(2048), blk, 0, stream>>>(
      RKP0, RKP1, nullptr, nullptr, nullptr, nullptr, RK, nullptr, 1024);

  extract_vt<<<dim3(32, 32), blk, 0, stream>>>(HEADS, VT);
  attn_fwd<<<dim3(32, 16), blk, 0, stream>>>(HEADS, RK, VT, rwb, rrb, ATTN);

  // X = input + attn @ o_w  (split-K 2)
  gemm_bt<0, 2><<<dim3(16, 8, 2), blk, 0, stream>>>(
      ATTN, WT_O, nullptr, nullptr, OWP0, OWP1, nullptr, nullptr, 2048, 1024, 1024);
  reduce_split<2, 2><<<dim3(2048), blk, 0, stream>>>(
      OWP0, OWP1, nullptr, nullptr, nullptr, input_, nullptr, X, 1024);

  // FFN: out = X + relu(LN(X) @ w1 + b1) @ w2 + b2
  ln_rows<<<dim3(2048), blk, 0, stream>>>(X, ln2g, ln2b, YN);
  gemm_bt<1, 1><<<dim3(16, 32), blk, 0, stream>>>(
      YN, WT_F1, H1, fb1, nullptr, nullptr, nullptr, nullptr, 2048, 4096, 1024);
  gemm_bt<0, 4><<<dim3(16, 8, 4), blk, 0, stream>>>(
      H1, WT_F2, nullptr, nullptr, F2P0, F2P1, F2P2, F2P3, 2048, 1024, 4096);
  reduce_split<4, 2><<<dim3(2048), blk, 0, stream>>>(
      F2P0, F2P1, F2P2, F2P3, fb2, X, nullptr, out, 1024);
}

// Round 5
// 242.513 us; speedup vs baseline: 2.8250x; 1.0858x over previous
//
#include <hip/hip_runtime.h>

// ---------------------------------------------------------------------------
// TransformerXL decoder layer on gfx950. bf16 MFMA everywhere matmul-shaped.
// Shapes: QLEN=MLEN=1024, KLEN=2048, BSZ=2, D=1024, H=16, DH=64, DFF=4096.
// Row convention for [len,b,*] tensors: flat row = pos*2 + b (matches jnp).
// R5: attn softmax de-shuffled: per-lane partial l (epilogue reduce), T13
//     defer-max (THR=12 log2), BD frag carry (d-window shifts 64/tile),
//     mask only in last tile, exp2f domain. ln pair merged.
// ---------------------------------------------------------------------------

typedef unsigned short u16;
typedef unsigned int   u32;
typedef __attribute__((ext_vector_type(8))) short bf16x8;   // MFMA A/B frag
typedef __attribute__((ext_vector_type(4))) float f32x4;    // MFMA C/D frag

struct alignas(16) U128 { u32 x[4]; };
struct alignas(16) F128 { float f[4]; };
struct alignas(8)  U64  { u32 x[2]; };

#define DEV static __device__ __forceinline__
#define MF(a, b, c) __builtin_amdgcn_mfma_f32_16x16x32_bf16((a), (b), (c), 0, 0, 0)

typedef __attribute__((address_space(1))) u32 as1_u32;
typedef __attribute__((address_space(3))) u32 as3_u32;
DEV void gload16(const void* g, void* l) {   // 16B/lane direct global->LDS
  __builtin_amdgcn_global_load_lds((as1_u32*)g, (as3_u32*)l, 16, 0, 0);
}

DEV u16 f2bf(float f) {                      // RNE fp32 -> bf16
  union { float f; u32 u; } v; v.f = f;
  u32 r = v.u + 0x7fffu + ((v.u >> 16) & 1u);
  return (u16)(r >> 16);
}
DEV float bf2f(u16 h) {
  union { u32 u; float f; } v; v.u = ((u32)h) << 16;
  return v.f;
}

// ---------------- LayerNorm over rows of 1024, f32 in -> bf16 out ----------
template <int TWO>
__global__ __launch_bounds__(256) void ln_rows(
    const float* __restrict__ src, const float* __restrict__ src2,
    const float* __restrict__ g, const float* __restrict__ b,
    u16* __restrict__ dst)
{
  int row = blockIdx.x, tid = threadIdx.x;
  const float* s_;
  if constexpr (TWO) s_ = (row < 2048) ? src + (size_t)row * 1024
                                       : src2 + (size_t)(row - 2048) * 1024;
  else s_ = src + (size_t)row * 1024;
  F128 v = ((const F128*)s_)[tid];
  float s = v.f[0] + v.f[1] + v.f[2] + v.f[3];
  float q = v.f[0]*v.f[0] + v.f[1]*v.f[1] + v.f[2]*v.f[2] + v.f[3]*v.f[3];
#pragma unroll
  for (int off = 1; off < 64; off <<= 1) {
    s += __shfl_xor(s, off); q += __shfl_xor(q, off);
  }
  __shared__ float sh[8];
  int wid = tid >> 6;
  if ((tid & 63) == 0) { sh[wid] = s; sh[4 + wid] = q; }
  __syncthreads();
  s = sh[0] + sh[1] + sh[2] + sh[3];
  q = sh[4] + sh[5] + sh[6] + sh[7];
  float mu = s * (1.0f / 1024.0f);
  float rs = rsqrtf(q * (1.0f / 1024.0f) - mu * mu + 1e-5f);
  F128 g4 = ((const F128*)g)[tid];
  F128 b4 = ((const F128*)b)[tid];
  union { u16 h[4]; U64 u; } o;
#pragma unroll
  for (int j = 0; j < 4; j++)
    o.h[j] = f2bf((v.f[j] - mu) * rs * g4.f[j] + b4.f[j]);
  *(U64*)(dst + (size_t)row * 1024 + tid * 4) = o.u;
}

// ---------------- W[K,N] f32 -> Wt[N,K] bf16 (64x64 LDS tiles) -------------
__global__ __launch_bounds__(256) void transpose_w(
    const float* __restrict__ W, u16* __restrict__ Wt, int K, int N)
{
  __shared__ float t[64][65];
  int k0 = blockIdx.x * 64, n0 = blockIdx.y * 64;
  int tid = threadIdx.x;
  int r = tid >> 6, c = tid & 63;
#pragma unroll
  for (int i = 0; i < 16; i++)
    t[r + i * 4][c] = W[(size_t)(k0 + r + i * 4) * N + n0 + c];
  __syncthreads();
#pragma unroll
  for (int i = 0; i < 16; i++) {
    int n = r + i * 4;
    Wt[(size_t)(n0 + n) * K + k0 + c] = f2bf(t[c][n]);
  }
}

// ---------------- flat f32 -> bf16 (pos_emb) -------------------------------
__global__ __launch_bounds__(256) void cvt_bf16(
    const float* __restrict__ s, u16* __restrict__ d, int n4)
{
  int i = blockIdx.x * 256 + threadIdx.x;
  if (i >= n4) return;
  F128 v = ((const F128*)s)[i];
  union { u16 h[4]; U64 u; } o;
#pragma unroll
  for (int j = 0; j < 4; j++) o.h[j] = f2bf(v.f[j]);
  ((U64*)d)[i] = o.u;
}

// ---------------- GEMM: C[M,N] = A[M,K]*Bt[N,K]^T (+epilogue) --------------
// 2-phase double-buffered: stage(t+1) -> ds_read+MFMA(t) -> barrier.
// 128x128 tile, BK=64, 4 waves (2x2 of 64x64), linear LDS, gload_lds w=16.
template <int EPI, int NSPLIT>
__global__ __launch_bounds__(256, 2) void gemm_bt(
    const u16* __restrict__ A, const u16* __restrict__ Bt,
    u16* __restrict__ outb, const float* __restrict__ bias,
    float* __restrict__ p0, float* __restrict__ p1,
    float* __restrict__ p2, float* __restrict__ p3,
    int M, int N, int K)
{
  __shared__ u16 As[2][128 * 64];
  __shared__ u16 Bs[2][128 * 64];
  int tid = threadIdx.x;
  int m0 = blockIdx.x * 128, n0 = blockIdx.y * 128;
  int lane = tid & 63, wid = tid >> 6;
  int wr = wid >> 1, wc = wid & 1;
  f32x4 acc[4][4] = {};

  const int Kc = K / NSPLIT;
  const int kbase = (NSPLIT > 1) ? (int)blockIdx.z * Kc : 0;

  const int lrow = wid * 8 + (lane >> 3);
  const int lcol = (lane & 7) * 8;
  const u16* Ag = A  + (size_t)(m0 + lrow) * K + kbase + lcol;
  const u16* Bg = Bt + (size_t)(n0 + lrow) * K + kbase + lcol;

  auto stage = [&](int buf, int k0) {
#pragma unroll
    for (int i = 0; i < 4; i++) {
      gload16(Ag + (size_t)i * 32 * K + k0, &As[buf][(i * 4 + wid) * 512]);
      gload16(Bg + (size_t)i * 32 * K + k0, &Bs[buf][(i * 4 + wid) * 512]);
    }
  };

  stage(0, 0);
  __syncthreads();                    // prologue drain
  int cur = 0;
  for (int k0 = 0; k0 < Kc; k0 += 64) {
    if (k0 + 64 < Kc) stage(cur ^ 1, k0 + 64);
    bf16x8 af[2][4], bfr[2][4];
#pragma unroll
    for (int kc = 0; kc < 2; kc++)
#pragma unroll
      for (int f = 0; f < 4; f++) {
        af[kc][f]  = *(const bf16x8*)&As[cur][(wr * 64 + f * 16 + (lane & 15)) * 64 + kc * 32 + (lane >> 4) * 8];
        bfr[kc][f] = *(const bf16x8*)&Bs[cur][(wc * 64 + f * 16 + (lane & 15)) * 64 + kc * 32 + (lane >> 4) * 8];
      }
    __builtin_amdgcn_s_setprio(1);
#pragma unroll
    for (int kc = 0; kc < 2; kc++)
#pragma unroll
      for (int fi = 0; fi < 4; fi++)
#pragma unroll
        for (int fj = 0; fj < 4; fj++)
          acc[fi][fj] = MF(af[kc][fi], bfr[kc][fj], acc[fi][fj]);
    __builtin_amdgcn_s_setprio(0);
    __syncthreads();                  // reads done + next buf staged
    cur ^= 1;
  }

  float* part = nullptr;
  if constexpr (NSPLIT > 1) {
    part = (blockIdx.z == 0) ? p0 : (blockIdx.z == 1) ? p1
         : (blockIdx.z == 2) ? p2 : p3;
  }
#pragma unroll
  for (int fi = 0; fi < 4; fi++)
#pragma unroll
    for (int fj = 0; fj < 4; fj++) {
      int col = n0 + wc * 64 + fj * 16 + (lane & 15);
      float bvv = (NSPLIT == 1 && bias != nullptr) ? bias[col] : 0.0f;
#pragma unroll
      for (int r = 0; r < 4; r++) {
        int row = m0 + wr * 64 + fi * 16 + (lane >> 4) * 4 + r;
        float v = acc[fi][fj][r] + bvv;
        if constexpr (NSPLIT > 1) {
          part[(size_t)row * N + col] = v;
        } else {
          if constexpr (EPI == 1) v = fmaxf(v, 0.0f);
          outb[(size_t)row * N + col] = f2bf(v);
        }
      }
    }
}

// ---------------- split-K reduce ------------------------------------------
template <int NS, int EPI>
__global__ __launch_bounds__(256) void reduce_split(
    const float* __restrict__ p0, const float* __restrict__ p1,
    const float* __restrict__ p2, const float* __restrict__ p3,
    const float* __restrict__ bias, const float* __restrict__ resid,
    u16* __restrict__ outb, float* __restrict__ outf, int N)
{
  int e = (blockIdx.x * 256 + threadIdx.x) * 4;
  F128 a = *(const F128*)(p0 + e);
  F128 b = *(const F128*)(p1 + e);
  float v[4];
#pragma unroll
  for (int j = 0; j < 4; j++) v[j] = a.f[j] + b.f[j];
  if constexpr (NS == 4) {
    F128 c = *(const F128*)(p2 + e);
    F128 d = *(const F128*)(p3 + e);
#pragma unroll
    for (int j = 0; j < 4; j++) v[j] += c.f[j] + d.f[j];
  }
  if constexpr (EPI == 2) {
    F128 rv = *(const F128*)(resid + e);
    int col = e % N;
    F128 o;
#pragma unroll
    for (int j = 0; j < 4; j++) {
      float bv = (bias != nullptr) ? bias[col + j] : 0.0f;
      o.f[j] = v[j] + bv + rv.f[j];
    }
    *(F128*)(outf + e) = o;
  } else {
    union { u16 h[4]; U64 u; } o;
#pragma unroll
    for (int j = 0; j < 4; j++) o.h[j] = f2bf(v[j]);
    *(U64*)(outb + e) = o.u;
  }
}

// ---------------- extract V from heads into Vt[bh][d][j] --------------------
__global__ __launch_bounds__(256) void extract_vt(
    const u16* __restrict__ heads, u16* __restrict__ Vt)
{
  __shared__ u16 t[64][72];
  int jt = blockIdx.x;           // j tile (0..31)
  int bh = blockIdx.y;           // 0..31
  int b = bh >> 4, h = bh & 15;
  int tid = threadIdx.x;
  int row = tid >> 2;
  int cc = (tid & 3) * 16;
#pragma unroll
  for (int i = 0; i < 2; i++)
    *(U128*)&t[row][cc + i * 8] =
        *(const U128*)&heads[(size_t)((jt * 64 + row) * 2 + b) * 3072 + 2048 + h * 64 + cc + i * 8];
  __syncthreads();
  int jc = tid & 63, dr = tid >> 6;
#pragma unroll
  for (int i = 0; i < 16; i++) {
    int d = dr + i * 4;
    Vt[((size_t)bh * 64 + d) * 2048 + jt * 64 + jc] = t[jc][d];
  }
}

// ---------------- fused rel-attention (flash-style) ------------------------
// block = (b,h, 64 q rows); 4 waves x 16 rows. K-tiles of 64.
// LDS: double-buffered K/V^T/Rband, column-XOR-swizzled, staged via
// global_load_lds with pre-swizzled global source. One barrier per tile.
// Softmax: log2-domain, per-lane partial l (epilogue reduce), defer-max
// (THR=12), BD frag carry across tiles, mask only in the last tile.
__global__ __launch_bounds__(256, 2) void attn_fwd(
    const u16* __restrict__ heads, const u16* __restrict__ rk,
    const u16* __restrict__ Vt, const float* __restrict__ rwb,
    const float* __restrict__ rrb, u16* __restrict__ attnout)
{
  // layout (u16): buf b at b*16384: K @+0 (4096), V @+4096 (4096), R @+8192 (8192)
  // Ps @32768 (64x72). Q overlay @0 during init (Qw 64x72, Qr at +4608).
  __shared__ u16 lds[37376];

  int tid = threadIdx.x, lane = tid & 63, wid = tid >> 6;
  int bh = blockIdx.x;                  // linear%8 = bh%8 -> same-XCD blocks share K/V
  int y = (int)blockIdx.y;
  int xt = (y < 8) ? y : 23 - y;        // CU pairing: work(y)+work(y+8) = 49 tiles
  int i0 = xt * 64;
  int b = bh >> 4, h = bh & 15;

  u16* Ps = lds + 32768;
  u16* Qw = lds;
  u16* Qr = lds + 4608;

  // ---- Q staging (overlay region; f32 bias add, bf16 store) ----
  for (int c = tid; c < 512; c += 256) {
    int row = c >> 3, c8 = (c & 7) * 8;
    union { U128 v; u16 h[8]; } in, ow, orr;
    in.v = *(const U128*)&heads[(size_t)((1024 + i0 + row) * 2 + b) * 3072 + h * 64 + c8];
#pragma unroll
    for (int j = 0; j < 8; j++) {
      float q = bf2f(in.h[j]);
      ow.h[j]  = f2bf(q + rwb[h * 64 + c8 + j]);
      orr.h[j] = f2bf(q + rrb[h * 64 + c8 + j]);
    }
    *(U128*)&Qw[row * 72 + c8] = ow.v;
    *(U128*)&Qr[row * 72 + c8] = orr.v;
  }
  __syncthreads();

  bf16x8 qwf[2], qrf[2];
  int qrow = wid * 16 + (lane & 15);
#pragma unroll
  for (int kc = 0; kc < 2; kc++) {
    qwf[kc] = *(const bf16x8*)&Qw[qrow * 72 + kc * 32 + (lane >> 4) * 8];
    qrf[kc] = *(const bf16x8*)&Qr[qrow * 72 + kc * 32 + (lane >> 4) * 8];
  }
  __syncthreads();                 // overlay reads done before gload overwrites

  // ---- staging (global_load_lds, source-side XOR swizzle) ----
  const int srow = lane >> 3;                    // row within 8-row group
  const int scol = 8 * ((lane & 7) ^ srow);      // pre-swizzled source col (u16)

  auto stage = [&](int buf, int t) {
    int j0 = t * 64;
    u16* base = lds + buf * 16384;
#pragma unroll
    for (int i = 0; i < 2; i++) {               // K: rows g8*8+srow
      int g8 = wid * 2 + i;
      int jr = j0 + g8 * 8 + srow;
      gload16(heads + (size_t)(jr * 2 + b) * 3072 + 1024 + h * 64 + scol,
              base + g8 * 512);
    }
#pragma unroll
    for (int i = 0; i < 2; i++) {               // V^T: rows = d
      int g8 = wid * 2 + i;
      int dr = g8 * 8 + srow;
      gload16(Vt + ((size_t)bh * 64 + dr) * 2048 + j0 + scol,
              base + 4096 + g8 * 512);
    }
    int rbase = 960 + j0 - i0;                  // R band (clamped rows -> masked)
#pragma unroll
    for (int i = 0; i < 4; i++) {
      int g8 = wid * 4 + i;
      int rr = rbase + g8 * 8 + srow;
      rr = rr < 0 ? 0 : (rr > 2047 ? 2047 : rr);
      gload16(rk + (size_t)rr * 1024 + h * 64 + scol,
              base + 8192 + g8 * 512);
    }
  };

  stage(0, 0);
  __syncthreads();                 // tile 0 staged

  float mrow[4], plrow[4];
  f32x4 o[4] = {};
  f32x4 bd[5];
#pragma unroll
  for (int r = 0; r < 4; r++) { mrow[r] = -1e30f; plrow[r] = 0.0f; }

  int nt = i0 / 64 + 17;           // covers j <= i0+63+1024
  const int roffw = 48 - wid * 16;
  const int g = lane >> 4, cc = lane & 15;
  const int rswz = 8 * (lane & 7); // read-side XOR (row&7 == lane&7 for all frags)
  const float SCL = 0.18033688f;   // 0.125 * log2(e)

  for (int t = 0; t < nt; t++) {
    const u16* base = lds + (t & 1) * 16384;
    if (t + 1 < nt) stage((t + 1) & 1, t + 1);  // overlaps compute below

    const u16* Kb = base;
    const u16* Vb = base + 4096;
    const u16* Rb = base + 8192;

    // AC = Qw.K^T ; BD band frags (fb=0 carried from prev tile, d-window +64)
    f32x4 sAC[4] = {};
    if (t == 0) bd[0] = (f32x4){0.f, 0.f, 0.f, 0.f};
#pragma unroll
    for (int fb = 1; fb < 5; fb++) bd[fb] = (f32x4){0.f, 0.f, 0.f, 0.f};
    __builtin_amdgcn_s_setprio(1);
#pragma unroll
    for (int kc = 0; kc < 2; kc++) {
      int cb = (kc * 32 + g * 8) ^ rswz;
#pragma unroll
      for (int fj = 0; fj < 4; fj++) {
        bf16x8 kf = *(const bf16x8*)&Kb[(fj * 16 + (lane & 15)) * 64 + cb];
        sAC[fj] = MF(qwf[kc], kf, sAC[fj]);
      }
      if (t == 0) {
        bf16x8 rf = *(const bf16x8*)&Rb[(roffw + (lane & 15)) * 64 + cb];
        bd[0] = MF(qrf[kc], rf, bd[0]);
      }
#pragma unroll
      for (int fb = 1; fb < 5; fb++) {
        bf16x8 rf = *(const bf16x8*)&Rb[(roffw + fb * 16 + (lane & 15)) * 64 + cb];
        bd[fb] = MF(qrf[kc], rf, bd[fb]);
      }
    }
    __builtin_amdgcn_s_setprio(0);

    // merge AC + diagonal-gathered BD (log2 domain)
    float p[4][4];
#pragma unroll
    for (int fj = 0; fj < 4; fj++)
#pragma unroll
      for (int r = 0; r < 4; r++) {
        int sh_ = 15 - 4 * g - r;                    // uniform per (quarter, r)
        int src = (lane & 48) | ((lane + sh_) & 15);
        float lo = __shfl(bd[fj][r], src);
        float hi = __shfl(bd[fj + 1][r], src);
        float bdv = (cc + sh_ < 16) ? lo : hi;
        p[fj][r] = (sAC[fj][r] + bdv) * SCL;
      }
    bd[0] = bd[4];                 // carry: next tile's fb=0 window

    if (t == nt - 1) {             // only the last tile has masked entries
#pragma unroll
      for (int fj = 0; fj < 4; fj++)
#pragma unroll
        for (int r = 0; r < 4; r++)
          if (fj * 16 + cc > 16 * wid + 4 * g + r) p[fj][r] = -1e30f;
    }

    float tmax[4];
#pragma unroll
    for (int r = 0; r < 4; r++)
      tmax[r] = fmaxf(fmaxf(p[0][r], p[1][r]), fmaxf(p[2][r], p[3][r]));

    bool ok = true;
#pragma unroll
    for (int r = 0; r < 4; r++) ok &= (tmax[r] <= mrow[r] + 12.0f);
    if (!__all(ok)) {              // rare: true max moved too far -> rescale
#pragma unroll
      for (int off = 1; off < 16; off <<= 1)
#pragma unroll
        for (int r = 0; r < 4; r++)
          tmax[r] = fmaxf(tmax[r], __shfl_xor(tmax[r], off));
#pragma unroll
      for (int r = 0; r < 4; r++) {
        float mn = fmaxf(mrow[r], tmax[r]);
        float ms = exp2f(mrow[r] - mn);
        mrow[r] = mn;
        plrow[r] *= ms;
#pragma unroll
        for (int fd = 0; fd < 4; fd++) o[fd][r] *= ms;
      }
    }

    // P = 2^(p-m) (bounded by 2^12), per-lane l partial, P -> LDS
#pragma unroll
    for (int fj = 0; fj < 4; fj++)
#pragma unroll
      for (int r = 0; r < 4; r++) {
        float e = exp2f(p[fj][r] - mrow[r]);
        plrow[r] += e;
        Ps[(wid * 16 + g * 4 + r) * 72 + fj * 16 + cc] = f2bf(e);
      }
    __builtin_amdgcn_s_setprio(1);
#pragma unroll
    for (int kc = 0; kc < 2; kc++) {
      bf16x8 pf = *(const bf16x8*)&Ps[(wid * 16 + (lane & 15)) * 72 + kc * 32 + g * 8];
      int cb = (kc * 32 + g * 8) ^ rswz;
#pragma unroll
      for (int fd = 0; fd < 4; fd++) {
        bf16x8 vf = *(const bf16x8*)&Vb[(fd * 16 + (lane & 15)) * 64 + cb];
        o[fd] = MF(pf, vf, o[fd]);
      }
    }
    __builtin_amdgcn_s_setprio(0);

    __syncthreads();               // drains stage(t+1) + protects buf reuse
  }

  // epilogue: single deferred l reduction (16-lane groups), then divide
#pragma unroll
  for (int off = 1; off < 16; off <<= 1)
#pragma unroll
    for (int r = 0; r < 4; r++)
      plrow[r] += __shfl_xor(plrow[r], off);
#pragma unroll
  for (int fd = 0; fd < 4; fd++)
#pragma unroll
    for (int r = 0; r < 4; r++) {
      int ii2 = (lane >> 4) * 4 + r;
      int row = (i0 + wid * 16 + ii2) * 2 + b;
      attnout[(size_t)row * 1024 + h * 64 + fd * 16 + (lane & 15)] = f2bf(o[fd][r] / plrow[r]);
    }
}

// ---------------------------------------------------------------------------
extern "C" void kernel_launch(void* const* d_in, const int* in_sizes, int n_in,
                              void* d_out, int out_size, void* d_ws, size_t ws_size,
                              hipStream_t stream)
{
  const float* input_ = (const float*)d_in[0];
  const float* mems   = (const float*)d_in[1];
  const float* pos    = (const float*)d_in[2];
  // d_in[3] = mask_tgt: analytic (j > i + 1024), never read
  const float* ln1g = (const float*)d_in[4];
  const float* ln1b = (const float*)d_in[5];
  const float* qkvw = (const float*)d_in[6];
  const float* qkvb = (const float*)d_in[7];
  const float* rw   = (const float*)d_in[8];
  const float* rwb  = (const float*)d_in[9];
  const float* rrb  = (const float*)d_in[10];
  const float* ow   = (const float*)d_in[11];
  const float* ln2g = (const float*)d_in[12];
  const float* ln2b = (const float*)d_in[13];
  const float* fw1  = (const float*)d_in[14];
  const float* fb1  = (const float*)d_in[15];
  const float* fw2  = (const float*)d_in[16];
  const float* fb2  = (const float*)d_in[17];
  float* out = (float*)d_out;

  char* w = (char*)d_ws;
  // workspace layout (bytes); later buffers alias dead earlier ones
  u16* WT_QKV = (u16*)(w + 0);          // [3072,1024] bf16   6291456
  u16* WT_R   = (u16*)(w + 6291456);    // [1024,1024]        2097152
  u16* WT_O   = (u16*)(w + 8388608);    // [1024,1024]        2097152
  u16* WT_F1  = (u16*)(w + 10485760);   // [4096,1024]        8388608
  u16* WT_F2  = (u16*)(w + 18874368);   // [1024,4096]        8388608
  u16* POSB   = (u16*)(w + 27262976);   // [2048,1024]        4194304
  u16* ATTN   = POSB;                   // alias: POSB dead after r_k GEMM
  u16* CATLN  = (u16*)(w + 31457280);   // [4096,1024]        8388608
  u16* HEADS  = (u16*)(w + 39845888);   // [4096,3072]        25165824
  u16* H1     = HEADS;                  // alias: heads dead after attention
  float* X    = (float*)(w + 56623104); // [2048,1024] f32    8388608 (heads tail)
  u16* RK     = (u16*)(w + 65011712);   // [2048,1024]        4194304
  u16* VT     = (u16*)(w + 69206016);   // [2,16,64,2048]     8388608
  u16* YN     = VT;                     // alias: VT dead after attention
  // total 77594624 bytes

  // split-K partial buffers (each 2048x1024 f32 = 8388608 B), aliasing dead
  // regions at the time the owning GEMM runs:
  float* RKP0 = (float*)(w + 31457280); // = CATLN (dead after QKV gemm)
  float* RKP1 = (float*)(w + 69206016); // = VT    (written later by extract_vt)
  float* OWP0 = (float*)(w + 39845888); // = HEADS head (dead after attn)
  float* OWP1 = (float*)(w + 48234496); // = HEADS +8.39MB
  float* F2P0 = (float*)(w + 0);        // = WT_QKV+WT_R (dead after attn/rk)
  float* F2P1 = (float*)(w + 10485760); // = WT_F1 (dead after f1 gemm)
  float* F2P2 = (float*)(w + 31457280); // = CATLN
  float* F2P3 = (float*)(w + 65011712); // = RK + YN-head (dead after f1)

  dim3 blk(256);

  // weight prep (fp32 -> bf16, transposed to [N,K])
  transpose_w<<<dim3(16, 48), blk, 0, stream>>>(qkvw, WT_QKV, 1024, 3072);
  transpose_w<<<dim3(16, 16), blk, 0, stream>>>(rw,   WT_R,   1024, 1024);
  transpose_w<<<dim3(16, 16), blk, 0, stream>>>(ow,   WT_O,   1024, 1024);
  transpose_w<<<dim3(16, 64), blk, 0, stream>>>(fw1,  WT_F1,  1024, 4096);
  transpose_w<<<dim3(64, 16), blk, 0, stream>>>(fw2,  WT_F2,  4096, 1024);
  cvt_bf16<<<dim3(2048), blk, 0, stream>>>(pos, POSB, 2048 * 1024 / 4);

  // pre-norm: catln rows 0..2047 = LN(mems), 2048..4095 = LN(input) (merged)
  ln_rows<1><<<dim3(4096), blk, 0, stream>>>(mems, input_, ln1g, ln1b, CATLN);

  // heads = catln @ qkv_w + qkv_b
  gemm_bt<0, 1><<<dim3(32, 24), blk, 0, stream>>>(
      CATLN, WT_QKV, HEADS, qkvb, nullptr, nullptr, nullptr, nullptr, 4096, 3072, 1024);
  // r_k = pos @ r_w (split-K 2; partials reuse CATLN which is now dead)
  gemm_bt<0, 2><<<dim3(16, 8, 2), blk, 0, stream>>>(
      POSB, WT_R, nullptr, nullptr, RKP0, RKP1, nullptr, nullptr, 2048, 1024, 1024);
  reduce_split<2, 0><<<dim3(2048), blk, 0, stream>>>(
      RKP0, RKP1, nullptr, nullptr, nullptr, nullptr, RK, nullptr, 1024);

  extract_vt<<<dim3(32, 32), blk, 0, stream>>>(HEADS, VT);
  attn_fwd<<<dim3(32, 16), blk, 0, stream>>>(HEADS, RK, VT, rwb, rrb, ATTN);

  // X = input + attn @ o_w  (split-K 2)
  gemm_bt<0, 2><<<dim3(16, 8, 2), blk, 0, stream>>>(
      ATTN, WT_O, nullptr, nullptr, OWP0, OWP1, nullptr, nullptr, 2048, 1024, 1024);
  reduce_split<2, 2><<<dim3(2048), blk, 0, stream>>>(
      OWP0, OWP1, nullptr, nullptr, nullptr, input_, nullptr, X, 1024);

  // FFN: out = X + relu(LN(X) @ w1 + b1) @ w2 + b2
  ln_rows<0><<<dim3(2048), blk, 0, stream>>>(X, nullptr, ln2g, ln2b, YN);
  gemm_bt<1, 1><<<dim3(16, 32), blk, 0, stream>>>(
      YN, WT_F1, H1, fb1, nullptr, nullptr, nullptr, nullptr, 2048, 4096, 1024);
  gemm_bt<0, 4><<<dim3(16, 8, 4), blk, 0, stream>>>(
      H1, WT_F2, nullptr, nullptr, F2P0, F2P1, F2P2, F2P3, 2048, 1024, 4096);
  reduce_split<4, 2><<<dim3(2048), blk, 0, stream>>>(
      F2P0, F2P1, F2P2, F2P3, fb2, X, nullptr, out, 1024);
}